// Round 18
// baseline (559.399 us; speedup 1.0000x reference)
//
#include <hip/hip_runtime.h>
#include <hip/hip_fp16.h>

static inline int ceil_div(int a, int b) { return (a + b - 1) / b; }

typedef _Float16 f16x2 __attribute__((ext_vector_type(2)));

#define PART_CHUNK 8192

// ================= setup: bucket histograms =================

__global__ __launch_bounds__(256) void k_pre(
    const int* __restrict__ dst_pp, int EPP, int NH1,
    const int* __restrict__ dst_pc, int EPC,
    int* __restrict__ btot1, int* __restrict__ btot2) {
    __shared__ int hist[256];
    int b = blockIdx.x;
    int g = b < NH1 ? 0 : 1;
    const int* dst = g ? dst_pc : dst_pp;
    int E = g ? EPC : EPP;
    int e0 = (g ? b - NH1 : b) * PART_CHUNK;
    if (e0 >= E) return;
    int e1 = e0 + PART_CHUNK < E ? e0 + PART_CHUNK : E;
    hist[threadIdx.x] = 0;
    __syncthreads();
    for (int i = e0 + threadIdx.x; i < e1; i += 256)
        atomicAdd(&hist[dst[i] >> 9], 1);
    __syncthreads();
    int h = hist[threadIdx.x];
    if (h) atomicAdd((g ? btot2 : btot1) + threadIdx.x, h);
}

// scan bucket totals -> bucket bases + staging cursors. Graph0 adds self loops
// analytically. One 256-thread block per graph.
__global__ void k_bscan(int NP, int NB1, const int* __restrict__ btot1,
                        int* __restrict__ bbase1, int* __restrict__ bcur1,
                        int NC, int NB2, const int* __restrict__ btot2,
                        int* __restrict__ bbase2, int* __restrict__ bcur2) {
    __shared__ int sm[256];
    int g = blockIdx.y;
    int NB = g ? NB2 : NB1;
    const int* btot = g ? btot2 : btot1;
    int* bbase = g ? bbase2 : bbase1;
    int* bcur = g ? bcur2 : bcur1;
    int tid = threadIdx.x;
    int v = 0;
    if (tid < NB) {
        v = btot[tid];
        if (!g) {
            int self = NP - (tid << 9);
            if (self > 512) self = 512;
            if (self < 0) self = 0;
            v += self;
        }
    }
    sm[tid] = v;
    __syncthreads();
    for (int off = 1; off < 256; off <<= 1) {
        int t = (tid >= off) ? sm[tid - off] : 0;
        __syncthreads();
        sm[tid] += t;
        __syncthreads();
    }
    if (tid < NB) {
        int base = tid ? sm[tid - 1] : 0;
        bbase[tid] = base;
        bcur[tid] = base;
    }
    if (tid == NB) bbase[tid] = sm[NB - 1];
}

// ================= helpers =================

__device__ __forceinline__ unsigned pkh_(float a, float b) {
    __half2 h = __floats2half2_rn(a, b);
    return *(unsigned*)&h;
}

__device__ __forceinline__ f16x2 pkc_(float a, float b) {
    f16x2 r;
    r.x = (_Float16)a;
    r.y = (_Float16)b;
    return r;
}

__device__ __forceinline__ uint2 ld8_(const void* p, unsigned boff) {
    return *(const uint2*)((const char*)p + boff);
}

__device__ __forceinline__ float4 unpk_(uint2 u) {
    f16x2 h01 = *(f16x2*)&u.x, h23 = *(f16x2*)&u.y;
    return make_float4((float)h01.x, (float)h01.y, (float)h23.x, (float)h23.y);
}

__device__ __forceinline__ float fdot2_(f16x2 a, f16x2 b, float c) {
#if __has_builtin(__builtin_amdgcn_fdot2)
    return __builtin_amdgcn_fdot2(a, b, c, false);
#else
    return fmaf((float)a.x, (float)b.x, fmaf((float)a.y, (float)b.y, c));
#endif
}

// ================= partA: radix-partition (low-VGPR, high-occupancy) =================

__global__ __launch_bounds__(256) void k_partA(
    int NP, const int* __restrict__ src_pp, const int* __restrict__ dst_pp, int E1,
    const int* __restrict__ src_pc, const int* __restrict__ dst_pc,
    const float* __restrict__ lab, int EPC, int NA1,
    int* __restrict__ bcur1, int* __restrict__ bcur2,
    uint2* __restrict__ stg1, uint2* __restrict__ stg2) {
    __shared__ int hist[256];
    __shared__ int base[256];
    int blk = blockIdx.x;
    int g = blk < NA1 ? 0 : 1;
    int E = g ? EPC : E1;
    int e0 = (g ? blk - NA1 : blk) * PART_CHUNK;
    if (e0 >= E) return;
    int e1 = e0 + PART_CHUNK < E ? e0 + PART_CHUNK : E;
    int tid = threadIdx.x;
    hist[tid] = 0;
    __syncthreads();
    for (int i = e0 + tid; i < e1; i += 256) {
        int d = g ? dst_pc[i] : (i < NP ? i : dst_pp[i - NP]);
        atomicAdd(&hist[d >> 9], 1);
    }
    __syncthreads();
    int h = hist[tid];
    base[tid] = h ? atomicAdd((g ? bcur2 : bcur1) + tid, h) : 0;
    hist[tid] = 0;
    __syncthreads();
    uint2* stg = g ? stg2 : stg1;
    for (int i = e0 + tid; i < e1; i += 256) {
        int d; unsigned pay;
        if (g) {
            d = dst_pc[i];
            unsigned hh = (unsigned)__half_as_ushort(__float2half_rn(lab[i]));
            pay = (unsigned)src_pc[i] | (hh << 16);
        } else {
            int s;
            if (i < NP) { d = i; s = i; } else { d = dst_pp[i - NP]; s = src_pp[i - NP]; }
            pay = (unsigned)s << 7;
        }
        int b = d >> 9;
        int r = atomicAdd(&hist[b], 1);
        stg[base[b] + r] = make_uint2(pay, (unsigned)d);
    }
}

// ================= input-transform GEMMs, lane = output column =================
// One block = 32 rows staged in LDS. Product blocks compute 3 outputs
// (hl1,hr1,hl2) from one staged tile; customer blocks compute hr2.
// All outputs fp16; stores are fully coalesced (one row = 128B contiguous).
// W used untransposed: W[j*64+lane] loads are coalesced and L2-hot.

__device__ __forceinline__ void gemm_cols(
    const float xs[32][64], int rw0, int lane, int row0, int n,
    const float* __restrict__ W, const float* __restrict__ b,
    void* __restrict__ o) {
    float bias = b[lane];
    float acc[8];
#pragma unroll
    for (int r = 0; r < 8; ++r) acc[r] = bias;
    for (int j = 0; j < 64; j += 4) {
        float wv0 = W[(j + 0) * 64 + lane];
        float wv1 = W[(j + 1) * 64 + lane];
        float wv2 = W[(j + 2) * 64 + lane];
        float wv3 = W[(j + 3) * 64 + lane];
#pragma unroll
        for (int r = 0; r < 8; ++r) {
            float4 xv = *(const float4*)&xs[rw0 + r][j];
            acc[r] = fmaf(xv.x, wv0, acc[r]);
            acc[r] = fmaf(xv.y, wv1, acc[r]);
            acc[r] = fmaf(xv.z, wv2, acc[r]);
            acc[r] = fmaf(xv.w, wv3, acc[r]);
        }
    }
#pragma unroll
    for (int r = 0; r < 8; ++r) {
        int row = row0 + rw0 + r;
        if (row < n) {
            __half hv = __float2half_rn(acc[r]);
            ((unsigned short*)o)[(size_t)row * 64 + lane] = __half_as_ushort(hv);
        }
    }
}

__global__ __launch_bounds__(256) void k_gemm2(
    int TP, const float* __restrict__ xp, int NP,
    const float* __restrict__ xc, int NC,
    const float* __restrict__ W1l, const float* __restrict__ b1l, void* __restrict__ hl1,
    const float* __restrict__ W1r, const float* __restrict__ b1r, void* __restrict__ hr1,
    const float* __restrict__ W2l, const float* __restrict__ b2l, void* __restrict__ hl2,
    const float* __restrict__ W2r, const float* __restrict__ b2r, void* __restrict__ hr2) {
    __shared__ float xs[32][64];
    int blk = blockIdx.x;
    int typeP = blk < TP;
    const float* x = typeP ? xp : xc;
    int n = typeP ? NP : NC;
    int row0 = (typeP ? blk : blk - TP) * 32;
    int t = threadIdx.x;
    for (int i = t; i < 512; i += 256) {   // 512 float4 = 32 rows x 64 floats
        int r = i >> 4, c = (i & 15) << 2;
        int rr = row0 + r < n ? row0 + r : n - 1;
        *(float4*)&xs[r][c] = *(const float4*)&x[(size_t)rr * 64 + c];
    }
    __syncthreads();
    int lane = t & 63;
    int rw0 = (t >> 6) * 8;
    if (typeP) {
        gemm_cols(xs, rw0, lane, row0, n, W1l, b1l, hl1);
        gemm_cols(xs, rw0, lane, row0, n, W1r, b1r, hr1);
        gemm_cols(xs, rw0, lane, row0, n, W2l, b2l, hl2);
    } else {
        gemm_cols(xs, rw0, lane, row0, n, W2r, b2r, hr2);
    }
}

// Phase B2: one workgroup per bucket. LDS per-node count -> LDS scan ->
// write off[] -> scatter to final CSR slots via LDS cursors.
__global__ __launch_bounds__(512) void k_partB2(
    int NB1, int NP, const int* __restrict__ bbase1, const uint2* __restrict__ stg1,
    unsigned* __restrict__ e1src, int* __restrict__ off1, int E1,
    int NC, const int* __restrict__ bbase2, const uint2* __restrict__ stg2,
    unsigned* __restrict__ epay, int* __restrict__ off2, int EPC) {
    __shared__ int cnt[512];
    __shared__ int cur[512];
    int b = blockIdx.x;
    int tid = threadIdx.x;
    if (b == 0 && tid < 32) {
        e1src[E1 + tid] = 0u;
        epay[EPC + tid] = 0u;
    }
    int n, n0, lo, hi;
    const uint2* stg; unsigned* dstp; int* off;
    if (b < NB1) {
        n = NP; n0 = b << 9; lo = bbase1[b]; hi = bbase1[b + 1];
        stg = stg1; dstp = e1src; off = off1;
    } else {
        int bb = b - NB1;
        n = NC; n0 = bb << 9; lo = bbase2[bb]; hi = bbase2[bb + 1];
        stg = stg2; dstp = epay; off = off2;
    }
    cnt[tid] = 0;
    __syncthreads();
    for (int i = lo + tid; i < hi; i += 512)
        atomicAdd(&cnt[stg[i].y & 511], 1);
    __syncthreads();
    int c0 = cnt[tid];
    for (int off_ = 1; off_ < 512; off_ <<= 1) {
        int t = (tid >= off_) ? cnt[tid - off_] : 0;
        __syncthreads();
        cnt[tid] += t;
        __syncthreads();
    }
    int pos0 = lo + cnt[tid] - c0;
    cur[tid] = pos0;
    int node = n0 + tid;
    if (node < n) off[node] = pos0;
    if (node == n - 1) off[n] = hi;
    __syncthreads();
    for (int i = lo + tid; i < hi; i += 512) {
        uint2 r = stg[i];
        int pos = atomicAdd(&cur[r.y & 511], 1);
        dstp[pos] = r.x;
    }
}

// ================= GATv2 building blocks =================

template <int CTRL>
__device__ __forceinline__ float dppadd_(float x) {
    int y = __builtin_amdgcn_update_dpp(0, __float_as_int(x), CTRL, 0xF, 0xF, true);
    return x + __int_as_float(y);
}

__device__ __forceinline__ float red16_(float c) {
    c = dppadd_<0xB1>(c);
    c = dppadd_<0x4E>(c);
    c = dppadd_<0x124>(c);
    c = dppadd_<0x128>(c);
    return c;
}

template <int HAS_EF>
__device__ __forceinline__ unsigned boff_(unsigned pr) {
    return HAS_EF ? ((pr & 0xFFFFu) << 7) : pr;
}

// Edge loop over fp16 rows; packed half2 math; no max-subtraction; DEPTH-4
// gather pipeline. Payload arrays zero-padded 32 entries.
template <int HAS_EF>
__device__ __forceinline__ void gat_pass(
    const void* __restrict__ hl, const unsigned* __restrict__ pay,
    int beg, int end, int slot, int g,
    f16x2 hr01, f16x2 hr23, f16x2 att01, f16x2 att23,
    f16x2 we01, f16x2 we23,
    float& s_run, float4& acc) {
    s_run = 0.f;
    acc = make_float4(0.f, 0.f, 0.f, 0.f);
    if (beg >= end) return;
    unsigned goff = (unsigned)g * 8u;
    int p = beg + slot;
    unsigned pr0 = pay[p], pr1 = pay[p + 4], pr2 = pay[p + 8],
             pr3 = pay[p + 12], pr4 = pay[p + 16];
    uint2 u0 = ld8_(hl, boff_<HAS_EF>(pr0) + goff);
    uint2 u1 = ld8_(hl, boff_<HAS_EF>(pr1) + goff);
    uint2 u2 = ld8_(hl, boff_<HAS_EF>(pr2) + goff);
    uint2 u3 = ld8_(hl, boff_<HAS_EF>(pr3) + goff);
    int pend = end + slot;
    for (; p < pend; p += 4) {
        unsigned prn = pay[p + 20];
        uint2 un = ld8_(hl, boff_<HAS_EF>(pr4) + goff);
        f16x2 m01 = *(f16x2*)&u0.x + hr01;
        f16x2 m23 = *(f16x2*)&u0.y + hr23;
        if (HAS_EF) {
            unsigned uh = pr0 & 0xFFFF0000u;
            unsigned lbu = uh | (uh >> 16);
            f16x2 lb2 = *(f16x2*)&lbu;
            m01 = lb2 * we01 + m01;
            m23 = lb2 * we23 + m23;
        }
        m01 = __builtin_elementwise_max(m01, m01 * (_Float16)0.2f);
        m23 = __builtin_elementwise_max(m23, m23 * (_Float16)0.2f);
        float c = fdot2_(m01, att01, 0.f);
        c = fdot2_(m23, att23, c);
        c = red16_(c);
        float w = (p < end) ? exp2f(c) : 0.f;
        s_run += w;
        float4 h = unpk_(u0);
        acc.x = fmaf(w, h.x, acc.x);
        acc.y = fmaf(w, h.y, acc.y);
        acc.z = fmaf(w, h.z, acc.z);
        acc.w = fmaf(w, h.w, acc.w);
        pr0 = pr1; pr1 = pr2; pr2 = pr3; pr3 = pr4; pr4 = prn;
        u0 = u1; u1 = u2; u2 = u3; u3 = un;
    }
}

__device__ __forceinline__ void slot_merge(float& s, float4& a) {
#pragma unroll
    for (int mask = 16; mask <= 32; mask <<= 1) {
        s += __shfl_xor(s, mask, 64);
        a.x += __shfl_xor(a.x, mask, 64);
        a.y += __shfl_xor(a.y, mask, 64);
        a.z += __shfl_xor(a.z, mask, 64);
        a.w += __shfl_xor(a.w, mask, 64);
    }
}

__device__ __forceinline__ void finish_row(float s_run, float4 a,
                                           const float* __restrict__ bias, int g,
                                           float o4[4]) {
    float inv = 1.f / (s_run + 1e-16f);
    float4 b4 = *(const float4*)(bias + g * 4);
    o4[0] = fmaxf(fmaf(a.x, inv, b4.x), 0.f);
    o4[1] = fmaxf(fmaf(a.y, inv, b4.y), 0.f);
    o4[2] = fmaxf(fmaf(a.z, inv, b4.z), 0.f);
    o4[3] = fmaxf(fmaf(a.w, inv, b4.w), 0.f);
}

// In-wave GEMV row@W via LDS row broadcast.
__device__ __forceinline__ float4 gemv64(const float o4[4], float* __restrict__ lds_row,
                                         int slot, int g, const float* __restrict__ W) {
    if (slot == 0) *(float4*)(lds_row + 4 * g) = make_float4(o4[0], o4[1], o4[2], o4[3]);
    __asm__ volatile("" ::: "memory");
    __builtin_amdgcn_wave_barrier();
    float4 r0 = *(const float4*)(lds_row + slot * 16 + 0);
    float4 r1 = *(const float4*)(lds_row + slot * 16 + 4);
    float4 r2 = *(const float4*)(lds_row + slot * 16 + 8);
    float4 r3 = *(const float4*)(lds_row + slot * 16 + 12);
    __asm__ volatile("" ::: "memory");
    __builtin_amdgcn_wave_barrier();
    float rv[16] = {r0.x, r0.y, r0.z, r0.w, r1.x, r1.y, r1.z, r1.w,
                    r2.x, r2.y, r2.z, r2.w, r3.x, r3.y, r3.z, r3.w};
    const float* Wp = W + slot * 16 * 64 + g * 4;
    float a0 = 0.f, a1 = 0.f, a2 = 0.f, a3 = 0.f;
#pragma unroll
    for (int t = 0; t < 16; ++t) {
        float4 w4 = *(const float4*)(Wp + t * 64);
        a0 = fmaf(rv[t], w4.x, a0); a1 = fmaf(rv[t], w4.y, a1);
        a2 = fmaf(rv[t], w4.z, a2); a3 = fmaf(rv[t], w4.w, a3);
    }
    a0 += __shfl_xor(a0, 16, 64); a0 += __shfl_xor(a0, 32, 64);
    a1 += __shfl_xor(a1, 16, 64); a1 += __shfl_xor(a1, 32, 64);
    a2 += __shfl_xor(a2, 16, 64); a2 += __shfl_xor(a2, 32, 64);
    a3 += __shfl_xor(a3, 16, 64); a3 += __shfl_xor(a3, 32, 64);
    return make_float4(a0, a1, a2, a3);
}

// Fused launch: conv1 (gat1, product nodes) + conv2 (gat2, customer nodes).
// Independent work -> overlapped in one grid. hr arrays are fp16 rows.
__global__ __launch_bounds__(256) void k_fuse1(
    int B1,
    const void* __restrict__ hl1, const void* __restrict__ hr1,
    const int* __restrict__ off1, const unsigned* __restrict__ e1src,
    const float* __restrict__ att1, const float* __restrict__ bias1,
    const float* __restrict__ W3l, const float* __restrict__ b3l,
    void* __restrict__ hl3, int NP,
    const void* __restrict__ hl2, const void* __restrict__ hr2,
    const int* __restrict__ off2, const unsigned* __restrict__ epay,
    const float* __restrict__ We2, const float* __restrict__ att2,
    const float* __restrict__ bias2,
    const float* __restrict__ W3r, const float* __restrict__ b3r,
    void* __restrict__ h3, int NC) {
    __shared__ float rowbuf[4][64];
    int lane = threadIdx.x & 63, slot = lane >> 4, g = lane & 15;
    float* lrow = rowbuf[threadIdx.x >> 6];
    const float L2E = 1.44269504f;
    if (blockIdx.x < (unsigned)B1) {
        int wid = (blockIdx.x * 256 + threadIdx.x) >> 6;
        if (wid >= NP) return;
        uint2 hu = *(const uint2*)((const char*)hr1 + (size_t)wid * 128 + g * 8);
        f16x2 hr01 = *(f16x2*)&hu.x, hr23 = *(f16x2*)&hu.y;
        float4 at = *(const float4*)(att1 + g * 4);
        f16x2 att01 = pkc_(at.x * L2E, at.y * L2E), att23 = pkc_(at.z * L2E, at.w * L2E);
        int beg = off1[wid], end = off1[wid + 1];
        float s; float4 a;
        gat_pass<0>(hl1, e1src, beg, end, slot, g, hr01, hr23, att01, att23, att01, att23, s, a);
        slot_merge(s, a);
        float o4[4];
        finish_row(s, a, bias1, g, o4);
        float4 o = gemv64(o4, lrow, slot, g, W3l);
        float4 bb = *(const float4*)(b3l + g * 4);
        o.x += bb.x; o.y += bb.y; o.z += bb.z; o.w += bb.w;
        if (slot == 0)
            *(uint2*)((char*)hl3 + (size_t)wid * 128 + g * 8) =
                make_uint2(pkh_(o.x, o.y), pkh_(o.z, o.w));
    } else {
        int wid = ((blockIdx.x - B1) * 256 + threadIdx.x) >> 6;
        if (wid >= NC) return;
        uint2 hu = *(const uint2*)((const char*)hr2 + (size_t)wid * 128 + g * 8);
        f16x2 hr01 = *(f16x2*)&hu.x, hr23 = *(f16x2*)&hu.y;
        float4 at = *(const float4*)(att2 + g * 4);
        f16x2 att01 = pkc_(at.x * L2E, at.y * L2E), att23 = pkc_(at.z * L2E, at.w * L2E);
        float4 wef = *(const float4*)(We2 + g * 4);
        f16x2 we01 = pkc_(wef.x, wef.y), we23 = pkc_(wef.z, wef.w);
        int beg = off2[wid], end = off2[wid + 1];
        float s; float4 a;
        gat_pass<1>(hl2, epay, beg, end, slot, g, hr01, hr23, att01, att23, we01, we23, s, a);
        slot_merge(s, a);
        float o4[4];
        finish_row(s, a, bias2, g, o4);
        float4 o = gemv64(o4, lrow, slot, g, W3r);
        float4 bb = *(const float4*)(b3r + g * 4);
        o.x += bb.x; o.y += bb.y; o.z += bb.z; o.w += bb.w;
        if (slot == 0)
            *(uint2*)((char*)h3 + (size_t)wid * 128 + g * 8) =
                make_uint2(pkh_(o.x, o.y), pkh_(o.z, o.w));
    }
}

// conv3: GAT(hl3 gathered, h3 streamed as hr, ef3) + relu + @Wlin+blin -> out
__global__ __launch_bounds__(256) void k_gat3(
    const void* __restrict__ hl3, const void* __restrict__ h3,
    const int* __restrict__ off2, const unsigned* __restrict__ epay,
    const float* __restrict__ We3, const float* __restrict__ att3,
    const float* __restrict__ bias3,
    const float* __restrict__ Wlin, const float* __restrict__ blin,
    float* __restrict__ outp, int ndst) {
    __shared__ float rowbuf[4][64];
    int wid = (blockIdx.x * blockDim.x + threadIdx.x) >> 6;
    if (wid >= ndst) return;
    int lane = threadIdx.x & 63, slot = lane >> 4, g = lane & 15;
    float* lrow = rowbuf[threadIdx.x >> 6];
    const float L2E = 1.44269504f;
    uint2 hu = *(const uint2*)((const char*)h3 + (size_t)wid * 128 + g * 8);
    f16x2 hr01 = *(f16x2*)&hu.x, hr23 = *(f16x2*)&hu.y;
    float4 at = *(const float4*)(att3 + g * 4);
    f16x2 att01 = pkc_(at.x * L2E, at.y * L2E), att23 = pkc_(at.z * L2E, at.w * L2E);
    float4 wef = *(const float4*)(We3 + g * 4);
    f16x2 we01 = pkc_(wef.x, wef.y), we23 = pkc_(wef.z, wef.w);
    int beg = off2[wid], end = off2[wid + 1];
    float s; float4 a;
    gat_pass<1>(hl3, epay, beg, end, slot, g, hr01, hr23, att01, att23, we01, we23, s, a);
    slot_merge(s, a);
    float o4[4];
    finish_row(s, a, bias3, g, o4);
    float4 o = gemv64(o4, lrow, slot, g, Wlin);
    float4 bl = *(const float4*)(blin + g * 4);
    o.x += bl.x; o.y += bl.y; o.z += bl.z; o.w += bl.w;
    if (slot == 0) *(float4*)(outp + (size_t)wid * 64 + g * 4) = o;
}

// ================= launch =================

extern "C" void kernel_launch(void* const* d_in, const int* in_sizes, int n_in,
                              void* d_out, int out_size, void* d_ws, size_t ws_size,
                              hipStream_t stream) {
    const float* x_p = (const float*)d_in[0];
    const float* x_c = (const float*)d_in[1];
    const float* elab_in = (const float*)d_in[2];
    const int* src_pp = (const int*)d_in[3];
    const int* dst_pp = (const int*)d_in[4];
    const int* src_pc = (const int*)d_in[5];
    const int* dst_pc = (const int*)d_in[6];
    const float* W1l = (const float*)d_in[7];
    const float* b1l = (const float*)d_in[8];
    const float* W1r = (const float*)d_in[9];
    const float* b1r = (const float*)d_in[10];
    const float* att1 = (const float*)d_in[11];
    const float* bias1 = (const float*)d_in[12];
    const float* W2l = (const float*)d_in[13];
    const float* b2l = (const float*)d_in[14];
    const float* W2r = (const float*)d_in[15];
    const float* b2r = (const float*)d_in[16];
    const float* We2 = (const float*)d_in[17];
    const float* att2 = (const float*)d_in[18];
    const float* bias2 = (const float*)d_in[19];
    const float* W3l = (const float*)d_in[20];
    const float* b3l = (const float*)d_in[21];
    const float* W3r = (const float*)d_in[22];
    const float* b3r = (const float*)d_in[23];
    const float* We3 = (const float*)d_in[24];
    const float* att3 = (const float*)d_in[25];
    const float* bias3 = (const float*)d_in[26];
    const float* Wlin = (const float*)d_in[27];
    const float* blin = (const float*)d_in[28];
    float* out = (float*)d_out;

    const int NP = in_sizes[0] / 64;
    const int NC = in_sizes[1] / 64;
    const int EPP = in_sizes[3];
    const int EPC = in_sizes[5];
    const int E1 = EPP + NP;
    const int NB1 = ceil_div(NP, 512), NB2 = ceil_div(NC, 512);

    // workspace layout (256B-aligned chunks) — all feature arrays fp16
    char* w = (char*)d_ws;
    auto alloc = [&](size_t bytes) { char* r = w; w += (bytes + 255) & ~(size_t)255; return r; };
    void* hl1 = alloc((size_t)NP * 128);
    void* hl2 = alloc((size_t)NP * 128);
    void* hl3 = alloc((size_t)NP * 128);
    void* h3 = alloc((size_t)NC * 128);
    void* hr1 = alloc((size_t)NP * 128);
    void* hr2 = alloc((size_t)NC * 128);
    unsigned* epay = (unsigned*)alloc((size_t)(EPC + 32) * 4);
    unsigned* e1src = (unsigned*)alloc((size_t)(E1 + 32) * 4);
    uint2* stg1 = (uint2*)alloc((size_t)E1 * 8);
    uint2* stg2 = (uint2*)alloc((size_t)EPC * 8);
    int* off1 = (int*)alloc((size_t)(NP + 1) * 4);
    int* off2 = (int*)alloc((size_t)(NC + 1) * 4);
    int* btot1 = (int*)alloc(256 * 4);
    int* btot2 = (int*)alloc(256 * 4);
    int* bbase1 = (int*)alloc(260 * 4);
    int* bbase2 = (int*)alloc(260 * 4);
    int* bcur1 = (int*)alloc(256 * 4);
    int* bcur2 = (int*)alloc(256 * 4);

    int NH1 = ceil_div(EPP, PART_CHUNK), NH2 = ceil_div(EPC, PART_CHUNK);
    int NA1 = ceil_div(E1, PART_CHUNK), NA2 = ceil_div(EPC, PART_CHUNK);

    (void)hipMemsetAsync(btot1, 0, 256 * 4, stream);
    (void)hipMemsetAsync(btot2, 0, 256 * 4, stream);

    // setup: bucket histograms
    k_pre<<<NH1 + NH2, 256, 0, stream>>>(dst_pp, EPP, NH1, dst_pc, EPC, btot1, btot2);
    k_bscan<<<dim3(1, 2), 256, 0, stream>>>(NP, NB1, btot1, bbase1, bcur1,
                                            NC, NB2, btot2, bbase2, bcur2);

    // edge partition (high-occupancy)
    k_partA<<<NA1 + NA2, 256, 0, stream>>>(
        NP, src_pp, dst_pp, E1, src_pc, dst_pc, elab_in, EPC, NA1,
        bcur1, bcur2, stg1, stg2);

    // input-transform GEMMs: lane=col, coalesced fp16 stores, untransposed W
    int TP = ceil_div(NP, 32), TC = ceil_div(NC, 32);
    k_gemm2<<<TP + TC, 256, 0, stream>>>(
        TP, x_p, NP, x_c, NC,
        W1l, b1l, hl1, W1r, b1r, hr1, W2l, b2l, hl2, W2r, b2r, hr2);

    // bucket-local CSR finalize
    k_partB2<<<NB1 + NB2, 512, 0, stream>>>(
        NB1, NP, bbase1, stg1, e1src, off1, E1,
        NC, bbase2, stg2, epay, off2, EPC);

    // fused conv1 + conv2 (independent) -> hl3, h3
    int B1 = ceil_div(NP, 4), B2 = ceil_div(NC, 4);
    k_fuse1<<<B1 + B2, 256, 0, stream>>>(
        B1, hl1, hr1, off1, e1src, att1, bias1, W3l, b3l, hl3, NP,
        hl2, hr2, off2, epay, We2, att2, bias2, W3r, b3r, h3, NC);

    // conv3 -> d_out
    k_gat3<<<ceil_div(NC * 64, 256), 256, 0, stream>>>(
        hl3, h3, off2, epay, We3, att3, bias3, Wlin, blin, out, NC);
}

// Round 19
// 379.724 us; speedup vs baseline: 1.4732x; 1.4732x over previous
//
#include <hip/hip_runtime.h>
#include <hip/hip_fp16.h>

static inline int ceil_div(int a, int b) { return (a + b - 1) / b; }

typedef _Float16 f16x2 __attribute__((ext_vector_type(2)));

#define PART_CHUNK 8192

// ================= setup: bucket histograms =================

__global__ __launch_bounds__(256) void k_pre(
    const int* __restrict__ dst_pp, int EPP, int NH1,
    const int* __restrict__ dst_pc, int EPC,
    int* __restrict__ btot1, int* __restrict__ btot2) {
    __shared__ int hist[256];
    int b = blockIdx.x;
    int g = b < NH1 ? 0 : 1;
    const int* dst = g ? dst_pc : dst_pp;
    int E = g ? EPC : EPP;
    int e0 = (g ? b - NH1 : b) * PART_CHUNK;
    if (e0 >= E) return;
    int e1 = e0 + PART_CHUNK < E ? e0 + PART_CHUNK : E;
    hist[threadIdx.x] = 0;
    __syncthreads();
    for (int i = e0 + threadIdx.x; i < e1; i += 256)
        atomicAdd(&hist[dst[i] >> 9], 1);
    __syncthreads();
    int h = hist[threadIdx.x];
    if (h) atomicAdd((g ? btot2 : btot1) + threadIdx.x, h);
}

// scan bucket totals -> bucket bases + staging cursors. Graph0 adds self loops
// analytically. One 256-thread block per graph.
__global__ void k_bscan(int NP, int NB1, const int* __restrict__ btot1,
                        int* __restrict__ bbase1, int* __restrict__ bcur1,
                        int NC, int NB2, const int* __restrict__ btot2,
                        int* __restrict__ bbase2, int* __restrict__ bcur2) {
    __shared__ int sm[256];
    int g = blockIdx.y;
    int NB = g ? NB2 : NB1;
    const int* btot = g ? btot2 : btot1;
    int* bbase = g ? bbase2 : bbase1;
    int* bcur = g ? bcur2 : bcur1;
    int tid = threadIdx.x;
    int v = 0;
    if (tid < NB) {
        v = btot[tid];
        if (!g) {
            int self = NP - (tid << 9);
            if (self > 512) self = 512;
            if (self < 0) self = 0;
            v += self;
        }
    }
    sm[tid] = v;
    __syncthreads();
    for (int off = 1; off < 256; off <<= 1) {
        int t = (tid >= off) ? sm[tid - off] : 0;
        __syncthreads();
        sm[tid] += t;
        __syncthreads();
    }
    if (tid < NB) {
        int base = tid ? sm[tid - 1] : 0;
        bbase[tid] = base;
        bcur[tid] = base;
    }
    if (tid == NB) bbase[tid] = sm[NB - 1];
}

// ================= helpers =================

__device__ __forceinline__ unsigned pkh_(float a, float b) {
    __half2 h = __floats2half2_rn(a, b);
    return *(unsigned*)&h;
}

__device__ __forceinline__ f16x2 pkc_(float a, float b) {
    f16x2 r;
    r.x = (_Float16)a;
    r.y = (_Float16)b;
    return r;
}

__device__ __forceinline__ uint2 ld8_(const void* p, unsigned boff) {
    return *(const uint2*)((const char*)p + boff);
}

__device__ __forceinline__ float4 unpk_(uint2 u) {
    f16x2 h01 = *(f16x2*)&u.x, h23 = *(f16x2*)&u.y;
    return make_float4((float)h01.x, (float)h01.y, (float)h23.x, (float)h23.y);
}

__device__ __forceinline__ float fdot2_(f16x2 a, f16x2 b, float c) {
#if __has_builtin(__builtin_amdgcn_fdot2)
    return __builtin_amdgcn_fdot2(a, b, c, false);
#else
    return fmaf((float)a.x, (float)b.x, fmaf((float)a.y, (float)b.y, c));
#endif
}

// ================= partA: radix-partition (low-VGPR, high-occupancy) =================

__global__ __launch_bounds__(256) void k_partA(
    int NP, const int* __restrict__ src_pp, const int* __restrict__ dst_pp, int E1,
    const int* __restrict__ src_pc, const int* __restrict__ dst_pc,
    const float* __restrict__ lab, int EPC, int NA1,
    int* __restrict__ bcur1, int* __restrict__ bcur2,
    uint2* __restrict__ stg1, uint2* __restrict__ stg2) {
    __shared__ int hist[256];
    __shared__ int base[256];
    int blk = blockIdx.x;
    int g = blk < NA1 ? 0 : 1;
    int E = g ? EPC : E1;
    int e0 = (g ? blk - NA1 : blk) * PART_CHUNK;
    if (e0 >= E) return;
    int e1 = e0 + PART_CHUNK < E ? e0 + PART_CHUNK : E;
    int tid = threadIdx.x;
    hist[tid] = 0;
    __syncthreads();
    for (int i = e0 + tid; i < e1; i += 256) {
        int d = g ? dst_pc[i] : (i < NP ? i : dst_pp[i - NP]);
        atomicAdd(&hist[d >> 9], 1);
    }
    __syncthreads();
    int h = hist[tid];
    base[tid] = h ? atomicAdd((g ? bcur2 : bcur1) + tid, h) : 0;
    hist[tid] = 0;
    __syncthreads();
    uint2* stg = g ? stg2 : stg1;
    for (int i = e0 + tid; i < e1; i += 256) {
        int d; unsigned pay;
        if (g) {
            d = dst_pc[i];
            unsigned hh = (unsigned)__half_as_ushort(__float2half_rn(lab[i]));
            pay = (unsigned)src_pc[i] | (hh << 16);
        } else {
            int s;
            if (i < NP) { d = i; s = i; } else { d = dst_pp[i - NP]; s = src_pp[i - NP]; }
            pay = (unsigned)s << 7;
        }
        int b = d >> 9;
        int r = atomicAdd(&hist[b], 1);
        stg[base[b] + r] = make_uint2(pay, (unsigned)d);
    }
}

// ================= input-transform GEMMs: one (tile, matrix) per block =================
// lane = output column, coalesced fp16 row stores, untransposed W.
// Product segments interleaved (m = blk%3) so 3 matrices sharing an x-tile
// run in adjacent blocks -> x tile L2-hot. One gemm per block keeps VGPR low
// (the round-18 multi-call version spilled: VGPR 256, 400MB scratch traffic).

__global__ __launch_bounds__(256) void k_gemm3(
    int TP, const float* __restrict__ xp, int NP,
    const float* __restrict__ xc, int NC,
    const float* __restrict__ W1l, const float* __restrict__ b1l, void* __restrict__ hl1,
    const float* __restrict__ W1r, const float* __restrict__ b1r, void* __restrict__ hr1,
    const float* __restrict__ W2l, const float* __restrict__ b2l, void* __restrict__ hl2,
    const float* __restrict__ W2r, const float* __restrict__ b2r, void* __restrict__ hr2) {
    __shared__ float xs[32][64];
    int blk = blockIdx.x;
    const float *x, *W, *b; void* o; int n, tile;
    if (blk < 3 * TP) {
        int m = blk % 3;
        tile = blk / 3;
        x = xp; n = NP;
        if (m == 0) { W = W1l; b = b1l; o = hl1; }
        else if (m == 1) { W = W1r; b = b1r; o = hr1; }
        else { W = W2l; b = b2l; o = hl2; }
    } else {
        tile = blk - 3 * TP;
        x = xc; n = NC; W = W2r; b = b2r; o = hr2;
    }
    int row0 = tile * 32;
    int t = threadIdx.x;
    for (int i = t; i < 512; i += 256) {   // 512 float4 = 32 rows x 64 floats
        int r = i >> 4, c = (i & 15) << 2;
        int rr = row0 + r < n ? row0 + r : n - 1;
        *(float4*)&xs[r][c] = *(const float4*)&x[(size_t)rr * 64 + c];
    }
    __syncthreads();
    int lane = t & 63;
    int rw0 = (t >> 6) * 8;
    float bias = b[lane];
    for (int gr = 0; gr < 2; ++gr) {
        int r0 = rw0 + gr * 4;
        float a0 = bias, a1 = bias, a2 = bias, a3 = bias;
#pragma unroll 2
        for (int j = 0; j < 64; j += 4) {
            float w0 = W[(j + 0) * 64 + lane];
            float w1 = W[(j + 1) * 64 + lane];
            float w2 = W[(j + 2) * 64 + lane];
            float w3 = W[(j + 3) * 64 + lane];
            float4 x0 = *(const float4*)&xs[r0 + 0][j];
            float4 x1 = *(const float4*)&xs[r0 + 1][j];
            float4 x2 = *(const float4*)&xs[r0 + 2][j];
            float4 x3 = *(const float4*)&xs[r0 + 3][j];
            a0 = fmaf(x0.x, w0, a0); a0 = fmaf(x0.y, w1, a0);
            a0 = fmaf(x0.z, w2, a0); a0 = fmaf(x0.w, w3, a0);
            a1 = fmaf(x1.x, w0, a1); a1 = fmaf(x1.y, w1, a1);
            a1 = fmaf(x1.z, w2, a1); a1 = fmaf(x1.w, w3, a1);
            a2 = fmaf(x2.x, w0, a2); a2 = fmaf(x2.y, w1, a2);
            a2 = fmaf(x2.z, w2, a2); a2 = fmaf(x2.w, w3, a2);
            a3 = fmaf(x3.x, w0, a3); a3 = fmaf(x3.y, w1, a3);
            a3 = fmaf(x3.z, w2, a3); a3 = fmaf(x3.w, w3, a3);
        }
        float acc[4] = {a0, a1, a2, a3};
#pragma unroll
        for (int r = 0; r < 4; ++r) {
            int row = row0 + r0 + r;
            if (row < n) {
                __half hv = __float2half_rn(acc[r]);
                ((unsigned short*)o)[(size_t)row * 64 + lane] = __half_as_ushort(hv);
            }
        }
    }
}

// Phase B2: one workgroup per bucket. LDS per-node count -> LDS scan ->
// write off[] -> scatter to final CSR slots via LDS cursors.
__global__ __launch_bounds__(512) void k_partB2(
    int NB1, int NP, const int* __restrict__ bbase1, const uint2* __restrict__ stg1,
    unsigned* __restrict__ e1src, int* __restrict__ off1, int E1,
    int NC, const int* __restrict__ bbase2, const uint2* __restrict__ stg2,
    unsigned* __restrict__ epay, int* __restrict__ off2, int EPC) {
    __shared__ int cnt[512];
    __shared__ int cur[512];
    int b = blockIdx.x;
    int tid = threadIdx.x;
    if (b == 0 && tid < 32) {
        e1src[E1 + tid] = 0u;
        epay[EPC + tid] = 0u;
    }
    int n, n0, lo, hi;
    const uint2* stg; unsigned* dstp; int* off;
    if (b < NB1) {
        n = NP; n0 = b << 9; lo = bbase1[b]; hi = bbase1[b + 1];
        stg = stg1; dstp = e1src; off = off1;
    } else {
        int bb = b - NB1;
        n = NC; n0 = bb << 9; lo = bbase2[bb]; hi = bbase2[bb + 1];
        stg = stg2; dstp = epay; off = off2;
    }
    cnt[tid] = 0;
    __syncthreads();
    for (int i = lo + tid; i < hi; i += 512)
        atomicAdd(&cnt[stg[i].y & 511], 1);
    __syncthreads();
    int c0 = cnt[tid];
    for (int off_ = 1; off_ < 512; off_ <<= 1) {
        int t = (tid >= off_) ? cnt[tid - off_] : 0;
        __syncthreads();
        cnt[tid] += t;
        __syncthreads();
    }
    int pos0 = lo + cnt[tid] - c0;
    cur[tid] = pos0;
    int node = n0 + tid;
    if (node < n) off[node] = pos0;
    if (node == n - 1) off[n] = hi;
    __syncthreads();
    for (int i = lo + tid; i < hi; i += 512) {
        uint2 r = stg[i];
        int pos = atomicAdd(&cur[r.y & 511], 1);
        dstp[pos] = r.x;
    }
}

// ================= GATv2 building blocks =================

template <int CTRL>
__device__ __forceinline__ float dppadd_(float x) {
    int y = __builtin_amdgcn_update_dpp(0, __float_as_int(x), CTRL, 0xF, 0xF, true);
    return x + __int_as_float(y);
}

__device__ __forceinline__ float red16_(float c) {
    c = dppadd_<0xB1>(c);
    c = dppadd_<0x4E>(c);
    c = dppadd_<0x124>(c);
    c = dppadd_<0x128>(c);
    return c;
}

template <int HAS_EF>
__device__ __forceinline__ unsigned boff_(unsigned pr) {
    return HAS_EF ? ((pr & 0xFFFFu) << 7) : pr;
}

// Edge loop over fp16 rows; packed half2 math; no max-subtraction; DEPTH-4
// gather pipeline. Payload arrays zero-padded 32 entries.
template <int HAS_EF>
__device__ __forceinline__ void gat_pass(
    const void* __restrict__ hl, const unsigned* __restrict__ pay,
    int beg, int end, int slot, int g,
    f16x2 hr01, f16x2 hr23, f16x2 att01, f16x2 att23,
    f16x2 we01, f16x2 we23,
    float& s_run, float4& acc) {
    s_run = 0.f;
    acc = make_float4(0.f, 0.f, 0.f, 0.f);
    if (beg >= end) return;
    unsigned goff = (unsigned)g * 8u;
    int p = beg + slot;
    unsigned pr0 = pay[p], pr1 = pay[p + 4], pr2 = pay[p + 8],
             pr3 = pay[p + 12], pr4 = pay[p + 16];
    uint2 u0 = ld8_(hl, boff_<HAS_EF>(pr0) + goff);
    uint2 u1 = ld8_(hl, boff_<HAS_EF>(pr1) + goff);
    uint2 u2 = ld8_(hl, boff_<HAS_EF>(pr2) + goff);
    uint2 u3 = ld8_(hl, boff_<HAS_EF>(pr3) + goff);
    int pend = end + slot;
    for (; p < pend; p += 4) {
        unsigned prn = pay[p + 20];
        uint2 un = ld8_(hl, boff_<HAS_EF>(pr4) + goff);
        f16x2 m01 = *(f16x2*)&u0.x + hr01;
        f16x2 m23 = *(f16x2*)&u0.y + hr23;
        if (HAS_EF) {
            unsigned uh = pr0 & 0xFFFF0000u;
            unsigned lbu = uh | (uh >> 16);
            f16x2 lb2 = *(f16x2*)&lbu;
            m01 = lb2 * we01 + m01;
            m23 = lb2 * we23 + m23;
        }
        m01 = __builtin_elementwise_max(m01, m01 * (_Float16)0.2f);
        m23 = __builtin_elementwise_max(m23, m23 * (_Float16)0.2f);
        float c = fdot2_(m01, att01, 0.f);
        c = fdot2_(m23, att23, c);
        c = red16_(c);
        float w = (p < end) ? exp2f(c) : 0.f;
        s_run += w;
        float4 h = unpk_(u0);
        acc.x = fmaf(w, h.x, acc.x);
        acc.y = fmaf(w, h.y, acc.y);
        acc.z = fmaf(w, h.z, acc.z);
        acc.w = fmaf(w, h.w, acc.w);
        pr0 = pr1; pr1 = pr2; pr2 = pr3; pr3 = pr4; pr4 = prn;
        u0 = u1; u1 = u2; u2 = u3; u3 = un;
    }
}

__device__ __forceinline__ void slot_merge(float& s, float4& a) {
#pragma unroll
    for (int mask = 16; mask <= 32; mask <<= 1) {
        s += __shfl_xor(s, mask, 64);
        a.x += __shfl_xor(a.x, mask, 64);
        a.y += __shfl_xor(a.y, mask, 64);
        a.z += __shfl_xor(a.z, mask, 64);
        a.w += __shfl_xor(a.w, mask, 64);
    }
}

__device__ __forceinline__ void finish_row(float s_run, float4 a,
                                           const float* __restrict__ bias, int g,
                                           float o4[4]) {
    float inv = 1.f / (s_run + 1e-16f);
    float4 b4 = *(const float4*)(bias + g * 4);
    o4[0] = fmaxf(fmaf(a.x, inv, b4.x), 0.f);
    o4[1] = fmaxf(fmaf(a.y, inv, b4.y), 0.f);
    o4[2] = fmaxf(fmaf(a.z, inv, b4.z), 0.f);
    o4[3] = fmaxf(fmaf(a.w, inv, b4.w), 0.f);
}

// In-wave GEMV row@W via LDS row broadcast.
__device__ __forceinline__ float4 gemv64(const float o4[4], float* __restrict__ lds_row,
                                         int slot, int g, const float* __restrict__ W) {
    if (slot == 0) *(float4*)(lds_row + 4 * g) = make_float4(o4[0], o4[1], o4[2], o4[3]);
    __asm__ volatile("" ::: "memory");
    __builtin_amdgcn_wave_barrier();
    float4 r0 = *(const float4*)(lds_row + slot * 16 + 0);
    float4 r1 = *(const float4*)(lds_row + slot * 16 + 4);
    float4 r2 = *(const float4*)(lds_row + slot * 16 + 8);
    float4 r3 = *(const float4*)(lds_row + slot * 16 + 12);
    __asm__ volatile("" ::: "memory");
    __builtin_amdgcn_wave_barrier();
    float rv[16] = {r0.x, r0.y, r0.z, r0.w, r1.x, r1.y, r1.z, r1.w,
                    r2.x, r2.y, r2.z, r2.w, r3.x, r3.y, r3.z, r3.w};
    const float* Wp = W + slot * 16 * 64 + g * 4;
    float a0 = 0.f, a1 = 0.f, a2 = 0.f, a3 = 0.f;
#pragma unroll
    for (int t = 0; t < 16; ++t) {
        float4 w4 = *(const float4*)(Wp + t * 64);
        a0 = fmaf(rv[t], w4.x, a0); a1 = fmaf(rv[t], w4.y, a1);
        a2 = fmaf(rv[t], w4.z, a2); a3 = fmaf(rv[t], w4.w, a3);
    }
    a0 += __shfl_xor(a0, 16, 64); a0 += __shfl_xor(a0, 32, 64);
    a1 += __shfl_xor(a1, 16, 64); a1 += __shfl_xor(a1, 32, 64);
    a2 += __shfl_xor(a2, 16, 64); a2 += __shfl_xor(a2, 32, 64);
    a3 += __shfl_xor(a3, 16, 64); a3 += __shfl_xor(a3, 32, 64);
    return make_float4(a0, a1, a2, a3);
}

// Fused launch: conv1 (gat1, product nodes) + conv2 (gat2, customer nodes).
// Independent work -> overlapped in one grid. hr arrays are fp16 rows.
__global__ __launch_bounds__(256) void k_fuse1(
    int B1,
    const void* __restrict__ hl1, const void* __restrict__ hr1,
    const int* __restrict__ off1, const unsigned* __restrict__ e1src,
    const float* __restrict__ att1, const float* __restrict__ bias1,
    const float* __restrict__ W3l, const float* __restrict__ b3l,
    void* __restrict__ hl3, int NP,
    const void* __restrict__ hl2, const void* __restrict__ hr2,
    const int* __restrict__ off2, const unsigned* __restrict__ epay,
    const float* __restrict__ We2, const float* __restrict__ att2,
    const float* __restrict__ bias2,
    const float* __restrict__ W3r, const float* __restrict__ b3r,
    void* __restrict__ h3, int NC) {
    __shared__ float rowbuf[4][64];
    int lane = threadIdx.x & 63, slot = lane >> 4, g = lane & 15;
    float* lrow = rowbuf[threadIdx.x >> 6];
    const float L2E = 1.44269504f;
    if (blockIdx.x < (unsigned)B1) {
        int wid = (blockIdx.x * 256 + threadIdx.x) >> 6;
        if (wid >= NP) return;
        uint2 hu = *(const uint2*)((const char*)hr1 + (size_t)wid * 128 + g * 8);
        f16x2 hr01 = *(f16x2*)&hu.x, hr23 = *(f16x2*)&hu.y;
        float4 at = *(const float4*)(att1 + g * 4);
        f16x2 att01 = pkc_(at.x * L2E, at.y * L2E), att23 = pkc_(at.z * L2E, at.w * L2E);
        int beg = off1[wid], end = off1[wid + 1];
        float s; float4 a;
        gat_pass<0>(hl1, e1src, beg, end, slot, g, hr01, hr23, att01, att23, att01, att23, s, a);
        slot_merge(s, a);
        float o4[4];
        finish_row(s, a, bias1, g, o4);
        float4 o = gemv64(o4, lrow, slot, g, W3l);
        float4 bb = *(const float4*)(b3l + g * 4);
        o.x += bb.x; o.y += bb.y; o.z += bb.z; o.w += bb.w;
        if (slot == 0)
            *(uint2*)((char*)hl3 + (size_t)wid * 128 + g * 8) =
                make_uint2(pkh_(o.x, o.y), pkh_(o.z, o.w));
    } else {
        int wid = ((blockIdx.x - B1) * 256 + threadIdx.x) >> 6;
        if (wid >= NC) return;
        uint2 hu = *(const uint2*)((const char*)hr2 + (size_t)wid * 128 + g * 8);
        f16x2 hr01 = *(f16x2*)&hu.x, hr23 = *(f16x2*)&hu.y;
        float4 at = *(const float4*)(att2 + g * 4);
        f16x2 att01 = pkc_(at.x * L2E, at.y * L2E), att23 = pkc_(at.z * L2E, at.w * L2E);
        float4 wef = *(const float4*)(We2 + g * 4);
        f16x2 we01 = pkc_(wef.x, wef.y), we23 = pkc_(wef.z, wef.w);
        int beg = off2[wid], end = off2[wid + 1];
        float s; float4 a;
        gat_pass<1>(hl2, epay, beg, end, slot, g, hr01, hr23, att01, att23, we01, we23, s, a);
        slot_merge(s, a);
        float o4[4];
        finish_row(s, a, bias2, g, o4);
        float4 o = gemv64(o4, lrow, slot, g, W3r);
        float4 bb = *(const float4*)(b3r + g * 4);
        o.x += bb.x; o.y += bb.y; o.z += bb.z; o.w += bb.w;
        if (slot == 0)
            *(uint2*)((char*)h3 + (size_t)wid * 128 + g * 8) =
                make_uint2(pkh_(o.x, o.y), pkh_(o.z, o.w));
    }
}

// conv3: GAT(hl3 gathered, h3 streamed as hr, ef3) + relu + @Wlin+blin -> out
__global__ __launch_bounds__(256) void k_gat3(
    const void* __restrict__ hl3, const void* __restrict__ h3,
    const int* __restrict__ off2, const unsigned* __restrict__ epay,
    const float* __restrict__ We3, const float* __restrict__ att3,
    const float* __restrict__ bias3,
    const float* __restrict__ Wlin, const float* __restrict__ blin,
    float* __restrict__ outp, int ndst) {
    __shared__ float rowbuf[4][64];
    int wid = (blockIdx.x * blockDim.x + threadIdx.x) >> 6;
    if (wid >= ndst) return;
    int lane = threadIdx.x & 63, slot = lane >> 4, g = lane & 15;
    float* lrow = rowbuf[threadIdx.x >> 6];
    const float L2E = 1.44269504f;
    uint2 hu = *(const uint2*)((const char*)h3 + (size_t)wid * 128 + g * 8);
    f16x2 hr01 = *(f16x2*)&hu.x, hr23 = *(f16x2*)&hu.y;
    float4 at = *(const float4*)(att3 + g * 4);
    f16x2 att01 = pkc_(at.x * L2E, at.y * L2E), att23 = pkc_(at.z * L2E, at.w * L2E);
    float4 wef = *(const float4*)(We3 + g * 4);
    f16x2 we01 = pkc_(wef.x, wef.y), we23 = pkc_(wef.z, wef.w);
    int beg = off2[wid], end = off2[wid + 1];
    float s; float4 a;
    gat_pass<1>(hl3, epay, beg, end, slot, g, hr01, hr23, att01, att23, we01, we23, s, a);
    slot_merge(s, a);
    float o4[4];
    finish_row(s, a, bias3, g, o4);
    float4 o = gemv64(o4, lrow, slot, g, Wlin);
    float4 bl = *(const float4*)(blin + g * 4);
    o.x += bl.x; o.y += bl.y; o.z += bl.z; o.w += bl.w;
    if (slot == 0) *(float4*)(outp + (size_t)wid * 64 + g * 4) = o;
}

// ================= launch =================

extern "C" void kernel_launch(void* const* d_in, const int* in_sizes, int n_in,
                              void* d_out, int out_size, void* d_ws, size_t ws_size,
                              hipStream_t stream) {
    const float* x_p = (const float*)d_in[0];
    const float* x_c = (const float*)d_in[1];
    const float* elab_in = (const float*)d_in[2];
    const int* src_pp = (const int*)d_in[3];
    const int* dst_pp = (const int*)d_in[4];
    const int* src_pc = (const int*)d_in[5];
    const int* dst_pc = (const int*)d_in[6];
    const float* W1l = (const float*)d_in[7];
    const float* b1l = (const float*)d_in[8];
    const float* W1r = (const float*)d_in[9];
    const float* b1r = (const float*)d_in[10];
    const float* att1 = (const float*)d_in[11];
    const float* bias1 = (const float*)d_in[12];
    const float* W2l = (const float*)d_in[13];
    const float* b2l = (const float*)d_in[14];
    const float* W2r = (const float*)d_in[15];
    const float* b2r = (const float*)d_in[16];
    const float* We2 = (const float*)d_in[17];
    const float* att2 = (const float*)d_in[18];
    const float* bias2 = (const float*)d_in[19];
    const float* W3l = (const float*)d_in[20];
    const float* b3l = (const float*)d_in[21];
    const float* W3r = (const float*)d_in[22];
    const float* b3r = (const float*)d_in[23];
    const float* We3 = (const float*)d_in[24];
    const float* att3 = (const float*)d_in[25];
    const float* bias3 = (const float*)d_in[26];
    const float* Wlin = (const float*)d_in[27];
    const float* blin = (const float*)d_in[28];
    float* out = (float*)d_out;

    const int NP = in_sizes[0] / 64;
    const int NC = in_sizes[1] / 64;
    const int EPP = in_sizes[3];
    const int EPC = in_sizes[5];
    const int E1 = EPP + NP;
    const int NB1 = ceil_div(NP, 512), NB2 = ceil_div(NC, 512);

    // workspace layout (256B-aligned chunks) — all feature arrays fp16
    char* w = (char*)d_ws;
    auto alloc = [&](size_t bytes) { char* r = w; w += (bytes + 255) & ~(size_t)255; return r; };
    void* hl1 = alloc((size_t)NP * 128);
    void* hl2 = alloc((size_t)NP * 128);
    void* hl3 = alloc((size_t)NP * 128);
    void* h3 = alloc((size_t)NC * 128);
    void* hr1 = alloc((size_t)NP * 128);
    void* hr2 = alloc((size_t)NC * 128);
    unsigned* epay = (unsigned*)alloc((size_t)(EPC + 32) * 4);
    unsigned* e1src = (unsigned*)alloc((size_t)(E1 + 32) * 4);
    uint2* stg1 = (uint2*)alloc((size_t)E1 * 8);
    uint2* stg2 = (uint2*)alloc((size_t)EPC * 8);
    int* off1 = (int*)alloc((size_t)(NP + 1) * 4);
    int* off2 = (int*)alloc((size_t)(NC + 1) * 4);
    int* btot1 = (int*)alloc(256 * 4);
    int* btot2 = (int*)alloc(256 * 4);
    int* bbase1 = (int*)alloc(260 * 4);
    int* bbase2 = (int*)alloc(260 * 4);
    int* bcur1 = (int*)alloc(256 * 4);
    int* bcur2 = (int*)alloc(256 * 4);

    int NH1 = ceil_div(EPP, PART_CHUNK), NH2 = ceil_div(EPC, PART_CHUNK);
    int NA1 = ceil_div(E1, PART_CHUNK), NA2 = ceil_div(EPC, PART_CHUNK);

    (void)hipMemsetAsync(btot1, 0, 256 * 4, stream);
    (void)hipMemsetAsync(btot2, 0, 256 * 4, stream);

    // setup: bucket histograms
    k_pre<<<NH1 + NH2, 256, 0, stream>>>(dst_pp, EPP, NH1, dst_pc, EPC, btot1, btot2);
    k_bscan<<<dim3(1, 2), 256, 0, stream>>>(NP, NB1, btot1, bbase1, bcur1,
                                            NC, NB2, btot2, bbase2, bcur2);

    // edge partition (high-occupancy)
    k_partA<<<NA1 + NA2, 256, 0, stream>>>(
        NP, src_pp, dst_pp, E1, src_pc, dst_pc, elab_in, EPC, NA1,
        bcur1, bcur2, stg1, stg2);

    // input-transform GEMMs: one (tile, matrix) per block, fp16 coalesced stores
    int TP = ceil_div(NP, 32), TC = ceil_div(NC, 32);
    k_gemm3<<<3 * TP + TC, 256, 0, stream>>>(
        TP, x_p, NP, x_c, NC,
        W1l, b1l, hl1, W1r, b1r, hr1, W2l, b2l, hl2, W2r, b2r, hr2);

    // bucket-local CSR finalize
    k_partB2<<<NB1 + NB2, 512, 0, stream>>>(
        NB1, NP, bbase1, stg1, e1src, off1, E1,
        NC, bbase2, stg2, epay, off2, EPC);

    // fused conv1 + conv2 (independent) -> hl3, h3
    int B1 = ceil_div(NP, 4), B2 = ceil_div(NC, 4);
    k_fuse1<<<B1 + B2, 256, 0, stream>>>(
        B1, hl1, hr1, off1, e1src, att1, bias1, W3l, b3l, hl3, NP,
        hl2, hr2, off2, epay, We2, att2, bias2, W3r, b3r, h3, NC);

    // conv3 -> d_out
    k_gat3<<<ceil_div(NC * 64, 256), 256, 0, stream>>>(
        hl3, h3, off2, epay, We3, att3, bias3, Wlin, blin, out, NC);
}

// Round 21
// 361.152 us; speedup vs baseline: 1.5489x; 1.0514x over previous
//
#include <hip/hip_runtime.h>
#include <hip/hip_fp16.h>

static inline int ceil_div(int a, int b) { return (a + b - 1) / b; }

typedef _Float16 f16x2 __attribute__((ext_vector_type(2)));

#define PART_CHUNK 8192

// ================= setup: bucket histograms =================

__global__ __launch_bounds__(256) void k_pre(
    const int* __restrict__ dst_pp, int EPP, int NH1,
    const int* __restrict__ dst_pc, int EPC,
    int* __restrict__ btot1, int* __restrict__ btot2) {
    __shared__ int hist[256];
    int b = blockIdx.x;
    int g = b < NH1 ? 0 : 1;
    const int* dst = g ? dst_pc : dst_pp;
    int E = g ? EPC : EPP;
    int e0 = (g ? b - NH1 : b) * PART_CHUNK;
    if (e0 >= E) return;
    int e1 = e0 + PART_CHUNK < E ? e0 + PART_CHUNK : E;
    hist[threadIdx.x] = 0;
    __syncthreads();
    for (int i = e0 + threadIdx.x; i < e1; i += 256)
        atomicAdd(&hist[dst[i] >> 9], 1);
    __syncthreads();
    int h = hist[threadIdx.x];
    if (h) atomicAdd((g ? btot2 : btot1) + threadIdx.x, h);
}

// scan bucket totals -> bucket bases + staging cursors. Graph0 adds self loops
// analytically. One 256-thread block per graph.
__global__ void k_bscan(int NP, int NB1, const int* __restrict__ btot1,
                        int* __restrict__ bbase1, int* __restrict__ bcur1,
                        int NC, int NB2, const int* __restrict__ btot2,
                        int* __restrict__ bbase2, int* __restrict__ bcur2) {
    __shared__ int sm[256];
    int g = blockIdx.y;
    int NB = g ? NB2 : NB1;
    const int* btot = g ? btot2 : btot1;
    int* bbase = g ? bbase2 : bbase1;
    int* bcur = g ? bcur2 : bcur1;
    int tid = threadIdx.x;
    int v = 0;
    if (tid < NB) {
        v = btot[tid];
        if (!g) {
            int self = NP - (tid << 9);
            if (self > 512) self = 512;
            if (self < 0) self = 0;
            v += self;
        }
    }
    sm[tid] = v;
    __syncthreads();
    for (int off = 1; off < 256; off <<= 1) {
        int t = (tid >= off) ? sm[tid - off] : 0;
        __syncthreads();
        sm[tid] += t;
        __syncthreads();
    }
    if (tid < NB) {
        int base = tid ? sm[tid - 1] : 0;
        bbase[tid] = base;
        bcur[tid] = base;
    }
    if (tid == NB) bbase[tid] = sm[NB - 1];
}

// ================= helpers =================

__device__ __forceinline__ unsigned pkh_(float a, float b) {
    __half2 h = __floats2half2_rn(a, b);
    return *(unsigned*)&h;
}

__device__ __forceinline__ f16x2 pkc_(float a, float b) {
    f16x2 r;
    r.x = (_Float16)a;
    r.y = (_Float16)b;
    return r;
}

__device__ __forceinline__ uint2 ld8_(const void* p, unsigned boff) {
    return *(const uint2*)((const char*)p + boff);
}

__device__ __forceinline__ float4 unpk_(uint2 u) {
    f16x2 h01 = *(f16x2*)&u.x, h23 = *(f16x2*)&u.y;
    return make_float4((float)h01.x, (float)h01.y, (float)h23.x, (float)h23.y);
}

__device__ __forceinline__ float fdot2_(f16x2 a, f16x2 b, float c) {
#if __has_builtin(__builtin_amdgcn_fdot2)
    return __builtin_amdgcn_fdot2(a, b, c, false);
#else
    return fmaf((float)a.x, (float)b.x, fmaf((float)a.y, (float)b.y, c));
#endif
}

// ================= partA: radix-partition (low-VGPR, high-occupancy) =================

__global__ __launch_bounds__(256) void k_partA(
    int NP, const int* __restrict__ src_pp, const int* __restrict__ dst_pp, int E1,
    const int* __restrict__ src_pc, const int* __restrict__ dst_pc,
    const float* __restrict__ lab, int EPC, int NA1,
    int* __restrict__ bcur1, int* __restrict__ bcur2,
    uint2* __restrict__ stg1, uint2* __restrict__ stg2) {
    __shared__ int hist[256];
    __shared__ int base[256];
    int blk = blockIdx.x;
    int g = blk < NA1 ? 0 : 1;
    int E = g ? EPC : E1;
    int e0 = (g ? blk - NA1 : blk) * PART_CHUNK;
    if (e0 >= E) return;
    int e1 = e0 + PART_CHUNK < E ? e0 + PART_CHUNK : E;
    int tid = threadIdx.x;
    hist[tid] = 0;
    __syncthreads();
    for (int i = e0 + tid; i < e1; i += 256) {
        int d = g ? dst_pc[i] : (i < NP ? i : dst_pp[i - NP]);
        atomicAdd(&hist[d >> 9], 1);
    }
    __syncthreads();
    int h = hist[tid];
    base[tid] = h ? atomicAdd((g ? bcur2 : bcur1) + tid, h) : 0;
    hist[tid] = 0;
    __syncthreads();
    uint2* stg = g ? stg2 : stg1;
    for (int i = e0 + tid; i < e1; i += 256) {
        int d; unsigned pay;
        if (g) {
            d = dst_pc[i];
            unsigned hh = (unsigned)__half_as_ushort(__float2half_rn(lab[i]));
            pay = (unsigned)src_pc[i] | (hh << 16);
        } else {
            int s;
            if (i < NP) { d = i; s = i; } else { d = dst_pp[i - NP]; s = src_pp[i - NP]; }
            pay = (unsigned)s << 7;
        }
        int b = d >> 9;
        int r = atomicAdd(&hist[b], 1);
        stg[base[b] + r] = make_uint2(pay, (unsigned)d);
    }
}

// ================= input-transform GEMMs: one (tile, matrix) per block =================
// lane = output column, coalesced fp16 row stores, untransposed W.

__global__ __launch_bounds__(256) void k_gemm3(
    int TP, const float* __restrict__ xp, int NP,
    const float* __restrict__ xc, int NC,
    const float* __restrict__ W1l, const float* __restrict__ b1l, void* __restrict__ hl1,
    const float* __restrict__ W1r, const float* __restrict__ b1r, void* __restrict__ hr1,
    const float* __restrict__ W2l, const float* __restrict__ b2l, void* __restrict__ hl2,
    const float* __restrict__ W2r, const float* __restrict__ b2r, void* __restrict__ hr2) {
    __shared__ float xs[32][64];
    int blk = blockIdx.x;
    const float *x, *W, *b; void* o; int n, tile;
    if (blk < 3 * TP) {
        int m = blk % 3;
        tile = blk / 3;
        x = xp; n = NP;
        if (m == 0) { W = W1l; b = b1l; o = hl1; }
        else if (m == 1) { W = W1r; b = b1r; o = hr1; }
        else { W = W2l; b = b2l; o = hl2; }
    } else {
        tile = blk - 3 * TP;
        x = xc; n = NC; W = W2r; b = b2r; o = hr2;
    }
    int row0 = tile * 32;
    int t = threadIdx.x;
    for (int i = t; i < 512; i += 256) {
        int r = i >> 4, c = (i & 15) << 2;
        int rr = row0 + r < n ? row0 + r : n - 1;
        *(float4*)&xs[r][c] = *(const float4*)&x[(size_t)rr * 64 + c];
    }
    __syncthreads();
    int lane = t & 63;
    int rw0 = (t >> 6) * 8;
    float bias = b[lane];
    for (int gr = 0; gr < 2; ++gr) {
        int r0 = rw0 + gr * 4;
        float a0 = bias, a1 = bias, a2 = bias, a3 = bias;
#pragma unroll 2
        for (int j = 0; j < 64; j += 4) {
            float w0 = W[(j + 0) * 64 + lane];
            float w1 = W[(j + 1) * 64 + lane];
            float w2 = W[(j + 2) * 64 + lane];
            float w3 = W[(j + 3) * 64 + lane];
            float4 x0 = *(const float4*)&xs[r0 + 0][j];
            float4 x1 = *(const float4*)&xs[r0 + 1][j];
            float4 x2 = *(const float4*)&xs[r0 + 2][j];
            float4 x3 = *(const float4*)&xs[r0 + 3][j];
            a0 = fmaf(x0.x, w0, a0); a0 = fmaf(x0.y, w1, a0);
            a0 = fmaf(x0.z, w2, a0); a0 = fmaf(x0.w, w3, a0);
            a1 = fmaf(x1.x, w0, a1); a1 = fmaf(x1.y, w1, a1);
            a1 = fmaf(x1.z, w2, a1); a1 = fmaf(x1.w, w3, a1);
            a2 = fmaf(x2.x, w0, a2); a2 = fmaf(x2.y, w1, a2);
            a2 = fmaf(x2.z, w2, a2); a2 = fmaf(x2.w, w3, a2);
            a3 = fmaf(x3.x, w0, a3); a3 = fmaf(x3.y, w1, a3);
            a3 = fmaf(x3.z, w2, a3); a3 = fmaf(x3.w, w3, a3);
        }
        float acc[4] = {a0, a1, a2, a3};
#pragma unroll
        for (int r = 0; r < 4; ++r) {
            int row = row0 + r0 + r;
            if (row < n) {
                __half hv = __float2half_rn(acc[r]);
                ((unsigned short*)o)[(size_t)row * 64 + lane] = __half_as_ushort(hv);
            }
        }
    }
}

// Phase B2: one workgroup per bucket. LDS per-node count -> LDS scan ->
// write off[] -> scatter to final CSR slots via LDS cursors.
__global__ __launch_bounds__(512) void k_partB2(
    int NB1, int NP, const int* __restrict__ bbase1, const uint2* __restrict__ stg1,
    unsigned* __restrict__ e1src, int* __restrict__ off1, int E1,
    int NC, const int* __restrict__ bbase2, const uint2* __restrict__ stg2,
    unsigned* __restrict__ epay, int* __restrict__ off2, int EPC) {
    __shared__ int cnt[512];
    __shared__ int cur[512];
    int b = blockIdx.x;
    int tid = threadIdx.x;
    if (b == 0 && tid < 32) {
        e1src[E1 + tid] = 0u;
        epay[EPC + tid] = 0u;
    }
    int n, n0, lo, hi;
    const uint2* stg; unsigned* dstp; int* off;
    if (b < NB1) {
        n = NP; n0 = b << 9; lo = bbase1[b]; hi = bbase1[b + 1];
        stg = stg1; dstp = e1src; off = off1;
    } else {
        int bb = b - NB1;
        n = NC; n0 = bb << 9; lo = bbase2[bb]; hi = bbase2[bb + 1];
        stg = stg2; dstp = epay; off = off2;
    }
    cnt[tid] = 0;
    __syncthreads();
    for (int i = lo + tid; i < hi; i += 512)
        atomicAdd(&cnt[stg[i].y & 511], 1);
    __syncthreads();
    int c0 = cnt[tid];
    for (int off_ = 1; off_ < 512; off_ <<= 1) {
        int t = (tid >= off_) ? cnt[tid - off_] : 0;
        __syncthreads();
        cnt[tid] += t;
        __syncthreads();
    }
    int pos0 = lo + cnt[tid] - c0;
    cur[tid] = pos0;
    int node = n0 + tid;
    if (node < n) off[node] = pos0;
    if (node == n - 1) off[n] = hi;
    __syncthreads();
    for (int i = lo + tid; i < hi; i += 512) {
        uint2 r = stg[i];
        int pos = atomicAdd(&cur[r.y & 511], 1);
        dstp[pos] = r.x;
    }
}

// ================= GATv2 building blocks =================

template <int CTRL>
__device__ __forceinline__ float dppadd_(float x) {
    int y = __builtin_amdgcn_update_dpp(0, __float_as_int(x), CTRL, 0xF, 0xF, true);
    return x + __int_as_float(y);
}

__device__ __forceinline__ float red16_(float c) {
    c = dppadd_<0xB1>(c);
    c = dppadd_<0x4E>(c);
    c = dppadd_<0x124>(c);
    c = dppadd_<0x128>(c);
    return c;
}

template <int HAS_EF>
__device__ __forceinline__ unsigned boff_(unsigned pr) {
    return HAS_EF ? ((pr & 0xFFFFu) << 7) : pr;
}

// Edge loop over fp16 rows; packed half2 math; no max-subtraction; DEPTH-4
// gather pipeline. Payload arrays zero-padded 32 entries.
template <int HAS_EF>
__device__ __forceinline__ void gat_pass(
    const void* __restrict__ hl, const unsigned* __restrict__ pay,
    int beg, int end, int slot, int g,
    f16x2 hr01, f16x2 hr23, f16x2 att01, f16x2 att23,
    f16x2 we01, f16x2 we23,
    float& s_run, float4& acc) {
    s_run = 0.f;
    acc = make_float4(0.f, 0.f, 0.f, 0.f);
    if (beg >= end) return;
    unsigned goff = (unsigned)g * 8u;
    int p = beg + slot;
    unsigned pr0 = pay[p], pr1 = pay[p + 4], pr2 = pay[p + 8],
             pr3 = pay[p + 12], pr4 = pay[p + 16];
    uint2 u0 = ld8_(hl, boff_<HAS_EF>(pr0) + goff);
    uint2 u1 = ld8_(hl, boff_<HAS_EF>(pr1) + goff);
    uint2 u2 = ld8_(hl, boff_<HAS_EF>(pr2) + goff);
    uint2 u3 = ld8_(hl, boff_<HAS_EF>(pr3) + goff);
    int pend = end + slot;
    for (; p < pend; p += 4) {
        unsigned prn = pay[p + 20];
        uint2 un = ld8_(hl, boff_<HAS_EF>(pr4) + goff);
        f16x2 m01 = *(f16x2*)&u0.x + hr01;
        f16x2 m23 = *(f16x2*)&u0.y + hr23;
        if (HAS_EF) {
            unsigned uh = pr0 & 0xFFFF0000u;
            unsigned lbu = uh | (uh >> 16);
            f16x2 lb2 = *(f16x2*)&lbu;
            m01 = lb2 * we01 + m01;
            m23 = lb2 * we23 + m23;
        }
        m01 = __builtin_elementwise_max(m01, m01 * (_Float16)0.2f);
        m23 = __builtin_elementwise_max(m23, m23 * (_Float16)0.2f);
        float c = fdot2_(m01, att01, 0.f);
        c = fdot2_(m23, att23, c);
        c = red16_(c);
        float w = (p < end) ? exp2f(c) : 0.f;
        s_run += w;
        float4 h = unpk_(u0);
        acc.x = fmaf(w, h.x, acc.x);
        acc.y = fmaf(w, h.y, acc.y);
        acc.z = fmaf(w, h.z, acc.z);
        acc.w = fmaf(w, h.w, acc.w);
        pr0 = pr1; pr1 = pr2; pr2 = pr3; pr3 = pr4; pr4 = prn;
        u0 = u1; u1 = u2; u2 = u3; u3 = un;
    }
}

__device__ __forceinline__ void slot_merge(float& s, float4& a) {
#pragma unroll
    for (int mask = 16; mask <= 32; mask <<= 1) {
        s += __shfl_xor(s, mask, 64);
        a.x += __shfl_xor(a.x, mask, 64);
        a.y += __shfl_xor(a.y, mask, 64);
        a.z += __shfl_xor(a.z, mask, 64);
        a.w += __shfl_xor(a.w, mask, 64);
    }
}

__device__ __forceinline__ void finish_row(float s_run, float4 a,
                                           const float* __restrict__ bias, int g,
                                           float o4[4]) {
    float inv = 1.f / (s_run + 1e-16f);
    float4 b4 = *(const float4*)(bias + g * 4);
    o4[0] = fmaxf(fmaf(a.x, inv, b4.x), 0.f);
    o4[1] = fmaxf(fmaf(a.y, inv, b4.y), 0.f);
    o4[2] = fmaxf(fmaf(a.z, inv, b4.z), 0.f);
    o4[3] = fmaxf(fmaf(a.w, inv, b4.w), 0.f);
}

// In-wave GEMV row@W via LDS row broadcast.
__device__ __forceinline__ float4 gemv64(const float o4[4], float* __restrict__ lds_row,
                                         int slot, int g, const float* __restrict__ W) {
    if (slot == 0) *(float4*)(lds_row + 4 * g) = make_float4(o4[0], o4[1], o4[2], o4[3]);
    __asm__ volatile("" ::: "memory");
    __builtin_amdgcn_wave_barrier();
    float4 r0 = *(const float4*)(lds_row + slot * 16 + 0);
    float4 r1 = *(const float4*)(lds_row + slot * 16 + 4);
    float4 r2 = *(const float4*)(lds_row + slot * 16 + 8);
    float4 r3 = *(const float4*)(lds_row + slot * 16 + 12);
    __asm__ volatile("" ::: "memory");
    __builtin_amdgcn_wave_barrier();
    float rv[16] = {r0.x, r0.y, r0.z, r0.w, r1.x, r1.y, r1.z, r1.w,
                    r2.x, r2.y, r2.z, r2.w, r3.x, r3.y, r3.z, r3.w};
    const float* Wp = W + slot * 16 * 64 + g * 4;
    float a0 = 0.f, a1 = 0.f, a2 = 0.f, a3 = 0.f;
#pragma unroll
    for (int t = 0; t < 16; ++t) {
        float4 w4 = *(const float4*)(Wp + t * 64);
        a0 = fmaf(rv[t], w4.x, a0); a1 = fmaf(rv[t], w4.y, a1);
        a2 = fmaf(rv[t], w4.z, a2); a3 = fmaf(rv[t], w4.w, a3);
    }
    a0 += __shfl_xor(a0, 16, 64); a0 += __shfl_xor(a0, 32, 64);
    a1 += __shfl_xor(a1, 16, 64); a1 += __shfl_xor(a1, 32, 64);
    a2 += __shfl_xor(a2, 16, 64); a2 += __shfl_xor(a2, 32, 64);
    a3 += __shfl_xor(a3, 16, 64); a3 += __shfl_xor(a3, 32, 64);
    return make_float4(a0, a1, a2, a3);
}

// conv1 (products): GAT + relu + @W3l + b3l -> hl3 (fp16). hr1 is fp16 rows.
__global__ __launch_bounds__(256) void k_gat1(
    const void* __restrict__ hl, const void* __restrict__ hr,
    const int* __restrict__ offs, const unsigned* __restrict__ esrc,
    const float* __restrict__ att, const float* __restrict__ bias,
    const float* __restrict__ W2, const float* __restrict__ b2,
    void* __restrict__ out2, int ndst) {
    __shared__ float rowbuf[4][64];
    int wid = (blockIdx.x * blockDim.x + threadIdx.x) >> 6;
    if (wid >= ndst) return;
    int lane = threadIdx.x & 63, slot = lane >> 4, g = lane & 15;
    float* lrow = rowbuf[threadIdx.x >> 6];
    const float L2E = 1.44269504f;
    uint2 hu = *(const uint2*)((const char*)hr + (size_t)wid * 128 + g * 8);
    f16x2 hr01 = *(f16x2*)&hu.x, hr23 = *(f16x2*)&hu.y;
    float4 at = *(const float4*)(att + g * 4);
    f16x2 att01 = pkc_(at.x * L2E, at.y * L2E), att23 = pkc_(at.z * L2E, at.w * L2E);
    int beg = offs[wid], end = offs[wid + 1];
    float s; float4 a;
    gat_pass<0>(hl, esrc, beg, end, slot, g, hr01, hr23, att01, att23, att01, att23, s, a);
    slot_merge(s, a);
    float o4[4];
    finish_row(s, a, bias, g, o4);
    float4 o = gemv64(o4, lrow, slot, g, W2);
    float4 bb = *(const float4*)(b2 + g * 4);
    o.x += bb.x; o.y += bb.y; o.z += bb.z; o.w += bb.w;
    if (slot == 0)
        *(uint2*)((char*)out2 + (size_t)wid * 128 + g * 8) =
            make_uint2(pkh_(o.x, o.y), pkh_(o.z, o.w));
}

// conv2 + conv3 fused per customer node: conv3's hr (h3) stays in registers;
// epay segment walked twice but h3 never round-trips through memory.
__global__ __launch_bounds__(256) void k_gat23(
    const void* __restrict__ hl2, const void* __restrict__ hr2,
    const void* __restrict__ hl3,
    const int* __restrict__ off2, const unsigned* __restrict__ epay,
    const float* __restrict__ We2, const float* __restrict__ att2, const float* __restrict__ bias2,
    const float* __restrict__ W3r, const float* __restrict__ b3r,
    const float* __restrict__ We3, const float* __restrict__ att3, const float* __restrict__ bias3,
    const float* __restrict__ Wlin, const float* __restrict__ blin,
    float* __restrict__ outp, int ndst) {
    __shared__ float rowbuf[4][64];
    int wid = (blockIdx.x * blockDim.x + threadIdx.x) >> 6;
    if (wid >= ndst) return;
    int lane = threadIdx.x & 63, slot = lane >> 4, g = lane & 15;
    float* lrow = rowbuf[threadIdx.x >> 6];
    int beg = off2[wid], end = off2[wid + 1];
    const float L2E = 1.44269504f;
    // ---- conv2 ----
    uint2 hu = *(const uint2*)((const char*)hr2 + (size_t)wid * 128 + g * 8);
    f16x2 hr01 = *(f16x2*)&hu.x, hr23 = *(f16x2*)&hu.y;
    float4 at = *(const float4*)(att2 + g * 4);
    f16x2 att01 = pkc_(at.x * L2E, at.y * L2E), att23 = pkc_(at.z * L2E, at.w * L2E);
    float4 wef = *(const float4*)(We2 + g * 4);
    f16x2 we01 = pkc_(wef.x, wef.y), we23 = pkc_(wef.z, wef.w);
    float s; float4 a;
    gat_pass<1>(hl2, epay, beg, end, slot, g, hr01, hr23, att01, att23, we01, we23, s, a);
    slot_merge(s, a);
    float o4[4];
    finish_row(s, a, bias2, g, o4);
    float4 h3 = gemv64(o4, lrow, slot, g, W3r);
    float4 bb = *(const float4*)(b3r + g * 4);
    h3.x += bb.x; h3.y += bb.y; h3.z += bb.z; h3.w += bb.w;
    // ---- conv3 (h3 in registers) ----
    hr01 = pkc_(h3.x, h3.y); hr23 = pkc_(h3.z, h3.w);
    at = *(const float4*)(att3 + g * 4);
    att01 = pkc_(at.x * L2E, at.y * L2E); att23 = pkc_(at.z * L2E, at.w * L2E);
    wef = *(const float4*)(We3 + g * 4);
    we01 = pkc_(wef.x, wef.y); we23 = pkc_(wef.z, wef.w);
    gat_pass<1>(hl3, epay, beg, end, slot, g, hr01, hr23, att01, att23, we01, we23, s, a);
    slot_merge(s, a);
    finish_row(s, a, bias3, g, o4);
    float4 o = gemv64(o4, lrow, slot, g, Wlin);
    float4 bl = *(const float4*)(blin + g * 4);
    o.x += bl.x; o.y += bl.y; o.z += bl.z; o.w += bl.w;
    if (slot == 0) *(float4*)(outp + (size_t)wid * 64 + g * 4) = o;
}

// ================= launch =================

extern "C" void kernel_launch(void* const* d_in, const int* in_sizes, int n_in,
                              void* d_out, int out_size, void* d_ws, size_t ws_size,
                              hipStream_t stream) {
    const float* x_p = (const float*)d_in[0];
    const float* x_c = (const float*)d_in[1];
    const float* elab_in = (const float*)d_in[2];
    const int* src_pp = (const int*)d_in[3];
    const int* dst_pp = (const int*)d_in[4];
    const int* src_pc = (const int*)d_in[5];
    const int* dst_pc = (const int*)d_in[6];
    const float* W1l = (const float*)d_in[7];
    const float* b1l = (const float*)d_in[8];
    const float* W1r = (const float*)d_in[9];
    const float* b1r = (const float*)d_in[10];
    const float* att1 = (const float*)d_in[11];
    const float* bias1 = (const float*)d_in[12];
    const float* W2l = (const float*)d_in[13];
    const float* b2l = (const float*)d_in[14];
    const float* W2r = (const float*)d_in[15];
    const float* b2r = (const float*)d_in[16];
    const float* We2 = (const float*)d_in[17];
    const float* att2 = (const float*)d_in[18];
    const float* bias2 = (const float*)d_in[19];
    const float* W3l = (const float*)d_in[20];
    const float* b3l = (const float*)d_in[21];
    const float* W3r = (const float*)d_in[22];
    const float* b3r = (const float*)d_in[23];
    const float* We3 = (const float*)d_in[24];
    const float* att3 = (const float*)d_in[25];
    const float* bias3 = (const float*)d_in[26];
    const float* Wlin = (const float*)d_in[27];
    const float* blin = (const float*)d_in[28];
    float* out = (float*)d_out;

    const int NP = in_sizes[0] / 64;
    const int NC = in_sizes[1] / 64;
    const int EPP = in_sizes[3];
    const int EPC = in_sizes[5];
    const int E1 = EPP + NP;
    const int NB1 = ceil_div(NP, 512), NB2 = ceil_div(NC, 512);

    // workspace layout (256B-aligned chunks) — all feature arrays fp16
    char* w = (char*)d_ws;
    auto alloc = [&](size_t bytes) { char* r = w; w += (bytes + 255) & ~(size_t)255; return r; };
    void* hl1 = alloc((size_t)NP * 128);
    void* hl2 = alloc((size_t)NP * 128);
    void* hl3 = alloc((size_t)NP * 128);
    void* hr1 = alloc((size_t)NP * 128);
    void* hr2 = alloc((size_t)NC * 128);
    unsigned* epay = (unsigned*)alloc((size_t)(EPC + 32) * 4);
    unsigned* e1src = (unsigned*)alloc((size_t)(E1 + 32) * 4);
    uint2* stg1 = (uint2*)alloc((size_t)E1 * 8);
    uint2* stg2 = (uint2*)alloc((size_t)EPC * 8);
    int* off1 = (int*)alloc((size_t)(NP + 1) * 4);
    int* off2 = (int*)alloc((size_t)(NC + 1) * 4);
    int* btot1 = (int*)alloc(256 * 4);
    int* btot2 = (int*)alloc(256 * 4);
    int* bbase1 = (int*)alloc(260 * 4);
    int* bbase2 = (int*)alloc(260 * 4);
    int* bcur1 = (int*)alloc(256 * 4);
    int* bcur2 = (int*)alloc(256 * 4);

    int NH1 = ceil_div(EPP, PART_CHUNK), NH2 = ceil_div(EPC, PART_CHUNK);
    int NA1 = ceil_div(E1, PART_CHUNK), NA2 = ceil_div(EPC, PART_CHUNK);

    (void)hipMemsetAsync(btot1, 0, 256 * 4, stream);
    (void)hipMemsetAsync(btot2, 0, 256 * 4, stream);

    // setup: bucket histograms
    k_pre<<<NH1 + NH2, 256, 0, stream>>>(dst_pp, EPP, NH1, dst_pc, EPC, btot1, btot2);
    k_bscan<<<dim3(1, 2), 256, 0, stream>>>(NP, NB1, btot1, bbase1, bcur1,
                                            NC, NB2, btot2, bbase2, bcur2);

    // edge partition (high-occupancy)
    k_partA<<<NA1 + NA2, 256, 0, stream>>>(
        NP, src_pp, dst_pp, E1, src_pc, dst_pc, elab_in, EPC, NA1,
        bcur1, bcur2, stg1, stg2);

    // input-transform GEMMs: one (tile, matrix) per block, fp16 coalesced stores
    int TP = ceil_div(NP, 32), TC = ceil_div(NC, 32);
    k_gemm3<<<3 * TP + TC, 256, 0, stream>>>(
        TP, x_p, NP, x_c, NC,
        W1l, b1l, hl1, W1r, b1r, hr1, W2l, b2l, hl2, W2r, b2r, hr2);

    // bucket-local CSR finalize
    k_partB2<<<NB1 + NB2, 512, 0, stream>>>(
        NB1, NP, bbase1, stg1, e1src, off1, E1,
        NC, bbase2, stg2, epay, off2, EPC);

    // conv1 -> hl3 (fp16)
    k_gat1<<<ceil_div(NP * 64, 256), 256, 0, stream>>>(
        hl1, hr1, off1, e1src, att1, bias1, W3l, b3l, hl3, NP);

    // conv2+conv3 fused -> d_out (h3 stays in registers)
    k_gat23<<<ceil_div(NC * 64, 256), 256, 0, stream>>>(
        hl2, hr2, hl3, off2, epay, We2, att2, bias2, W3r, b3r,
        We3, att3, bias3, Wlin, blin, out, NC);
}

// Round 22
// 333.989 us; speedup vs baseline: 1.6749x; 1.0813x over previous
//
#include <hip/hip_runtime.h>
#include <hip/hip_fp16.h>

static inline int ceil_div(int a, int b) { return (a + b - 1) / b; }

typedef _Float16 f16x2 __attribute__((ext_vector_type(2)));

#define PART_CHUNK 8192

// ================= setup: bucket histograms =================

__global__ __launch_bounds__(256) void k_pre(
    const int* __restrict__ dst_pp, int EPP, int NH1,
    const int* __restrict__ dst_pc, int EPC,
    int* __restrict__ btot1, int* __restrict__ btot2) {
    __shared__ int hist[256];
    int b = blockIdx.x;
    int g = b < NH1 ? 0 : 1;
    const int* dst = g ? dst_pc : dst_pp;
    int E = g ? EPC : EPP;
    int e0 = (g ? b - NH1 : b) * PART_CHUNK;
    if (e0 >= E) return;
    int e1 = e0 + PART_CHUNK < E ? e0 + PART_CHUNK : E;
    hist[threadIdx.x] = 0;
    __syncthreads();
    for (int i = e0 + threadIdx.x; i < e1; i += 256)
        atomicAdd(&hist[dst[i] >> 9], 1);
    __syncthreads();
    int h = hist[threadIdx.x];
    if (h) atomicAdd((g ? btot2 : btot1) + threadIdx.x, h);
}

// scan bucket totals -> bucket bases + staging cursors. Graph0 adds self loops
// analytically. One 256-thread block per graph.
__global__ void k_bscan(int NP, int NB1, const int* __restrict__ btot1,
                        int* __restrict__ bbase1, int* __restrict__ bcur1,
                        int NC, int NB2, const int* __restrict__ btot2,
                        int* __restrict__ bbase2, int* __restrict__ bcur2) {
    __shared__ int sm[256];
    int g = blockIdx.y;
    int NB = g ? NB2 : NB1;
    const int* btot = g ? btot2 : btot1;
    int* bbase = g ? bbase2 : bbase1;
    int* bcur = g ? bcur2 : bcur1;
    int tid = threadIdx.x;
    int v = 0;
    if (tid < NB) {
        v = btot[tid];
        if (!g) {
            int self = NP - (tid << 9);
            if (self > 512) self = 512;
            if (self < 0) self = 0;
            v += self;
        }
    }
    sm[tid] = v;
    __syncthreads();
    for (int off = 1; off < 256; off <<= 1) {
        int t = (tid >= off) ? sm[tid - off] : 0;
        __syncthreads();
        sm[tid] += t;
        __syncthreads();
    }
    if (tid < NB) {
        int base = tid ? sm[tid - 1] : 0;
        bbase[tid] = base;
        bcur[tid] = base;
    }
    if (tid == NB) bbase[tid] = sm[NB - 1];
}

// ================= helpers =================

__device__ __forceinline__ unsigned pkh_(float a, float b) {
    __half2 h = __floats2half2_rn(a, b);
    return *(unsigned*)&h;
}

__device__ __forceinline__ f16x2 pkc_(float a, float b) {
    f16x2 r;
    r.x = (_Float16)a;
    r.y = (_Float16)b;
    return r;
}

__device__ __forceinline__ uint2 ld8_(const void* p, unsigned boff) {
    return *(const uint2*)((const char*)p + boff);
}

__device__ __forceinline__ float4 unpk_(uint2 u) {
    f16x2 h01 = *(f16x2*)&u.x, h23 = *(f16x2*)&u.y;
    return make_float4((float)h01.x, (float)h01.y, (float)h23.x, (float)h23.y);
}

__device__ __forceinline__ float fdot2_(f16x2 a, f16x2 b, float c) {
#if __has_builtin(__builtin_amdgcn_fdot2)
    return __builtin_amdgcn_fdot2(a, b, c, false);
#else
    return fmaf((float)a.x, (float)b.x, fmaf((float)a.y, (float)b.y, c));
#endif
}

// ================= fused partA (radix-partition) + input GEMMs =================
// Safe to fuse now: the gemm branch holds only ~48 VGPRs (round-15's failure
// was the xr[64] GEMM at VGPR 92 -> 20% occupancy for the whole kernel).

__global__ __launch_bounds__(256) void k_AG(
    int NP, const int* __restrict__ src_pp, const int* __restrict__ dst_pp, int E1,
    const int* __restrict__ src_pc, const int* __restrict__ dst_pc,
    const float* __restrict__ lab, int EPC, int NA1, int NA2,
    int* __restrict__ bcur1, int* __restrict__ bcur2,
    uint2* __restrict__ stg1, uint2* __restrict__ stg2,
    int TP, const float* __restrict__ xp,
    const float* __restrict__ xc, int NC,
    const float* __restrict__ W1l, const float* __restrict__ b1l, void* __restrict__ hl1,
    const float* __restrict__ W1r, const float* __restrict__ b1r, void* __restrict__ hr1,
    const float* __restrict__ W2l, const float* __restrict__ b2l, void* __restrict__ hl2,
    const float* __restrict__ W2r, const float* __restrict__ b2r, void* __restrict__ hr2) {
    __shared__ float xs[32][64];   // gemm branch (8KB); partA overlays first 2KB
    int* hist = (int*)&xs[0][0];
    int* base = hist + 256;
    int blk = blockIdx.x;
    if (blk < NA1 + NA2) {
        // ---- partA ----
        int g = blk < NA1 ? 0 : 1;
        int E = g ? EPC : E1;
        int e0 = (g ? blk - NA1 : blk) * PART_CHUNK;
        if (e0 >= E) return;
        int e1 = e0 + PART_CHUNK < E ? e0 + PART_CHUNK : E;
        int tid = threadIdx.x;
        hist[tid] = 0;
        __syncthreads();
        for (int i = e0 + tid; i < e1; i += 256) {
            int d = g ? dst_pc[i] : (i < NP ? i : dst_pp[i - NP]);
            atomicAdd(&hist[d >> 9], 1);
        }
        __syncthreads();
        int h = hist[tid];
        base[tid] = h ? atomicAdd((g ? bcur2 : bcur1) + tid, h) : 0;
        hist[tid] = 0;
        __syncthreads();
        uint2* stg = g ? stg2 : stg1;
        for (int i = e0 + tid; i < e1; i += 256) {
            int d; unsigned pay;
            if (g) {
                d = dst_pc[i];
                unsigned hh = (unsigned)__half_as_ushort(__float2half_rn(lab[i]));
                pay = (unsigned)src_pc[i] | (hh << 16);
            } else {
                int s;
                if (i < NP) { d = i; s = i; } else { d = dst_pp[i - NP]; s = src_pp[i - NP]; }
                pay = (unsigned)s << 7;
            }
            int b = d >> 9;
            int r = atomicAdd(&hist[b], 1);
            stg[base[b] + r] = make_uint2(pay, (unsigned)d);
        }
    } else {
        // ---- input GEMM: one (tile, matrix) per block ----
        int gb = blk - NA1 - NA2;
        const float *x, *W, *b; void* o; int n, tile;
        if (gb < 3 * TP) {
            int m = gb % 3;
            tile = gb / 3;
            x = xp; n = NP;
            if (m == 0) { W = W1l; b = b1l; o = hl1; }
            else if (m == 1) { W = W1r; b = b1r; o = hr1; }
            else { W = W2l; b = b2l; o = hl2; }
        } else {
            tile = gb - 3 * TP;
            x = xc; n = NC; W = W2r; b = b2r; o = hr2;
        }
        int row0 = tile * 32;
        int t = threadIdx.x;
        for (int i = t; i < 512; i += 256) {
            int r = i >> 4, c = (i & 15) << 2;
            int rr = row0 + r < n ? row0 + r : n - 1;
            *(float4*)&xs[r][c] = *(const float4*)&x[(size_t)rr * 64 + c];
        }
        __syncthreads();
        int lane = t & 63;
        int rw0 = (t >> 6) * 8;
        float bias = b[lane];
        for (int gr = 0; gr < 2; ++gr) {
            int r0 = rw0 + gr * 4;
            float a0 = bias, a1 = bias, a2 = bias, a3 = bias;
#pragma unroll 2
            for (int j = 0; j < 64; j += 4) {
                float w0 = W[(j + 0) * 64 + lane];
                float w1 = W[(j + 1) * 64 + lane];
                float w2 = W[(j + 2) * 64 + lane];
                float w3 = W[(j + 3) * 64 + lane];
                float4 x0 = *(const float4*)&xs[r0 + 0][j];
                float4 x1 = *(const float4*)&xs[r0 + 1][j];
                float4 x2 = *(const float4*)&xs[r0 + 2][j];
                float4 x3 = *(const float4*)&xs[r0 + 3][j];
                a0 = fmaf(x0.x, w0, a0); a0 = fmaf(x0.y, w1, a0);
                a0 = fmaf(x0.z, w2, a0); a0 = fmaf(x0.w, w3, a0);
                a1 = fmaf(x1.x, w0, a1); a1 = fmaf(x1.y, w1, a1);
                a1 = fmaf(x1.z, w2, a1); a1 = fmaf(x1.w, w3, a1);
                a2 = fmaf(x2.x, w0, a2); a2 = fmaf(x2.y, w1, a2);
                a2 = fmaf(x2.z, w2, a2); a2 = fmaf(x2.w, w3, a2);
                a3 = fmaf(x3.x, w0, a3); a3 = fmaf(x3.y, w1, a3);
                a3 = fmaf(x3.z, w2, a3); a3 = fmaf(x3.w, w3, a3);
            }
            float acc[4] = {a0, a1, a2, a3};
#pragma unroll
            for (int r = 0; r < 4; ++r) {
                int row = row0 + r0 + r;
                if (row < n) {
                    __half hv = __float2half_rn(acc[r]);
                    ((unsigned short*)o)[(size_t)row * 64 + lane] = __half_as_ushort(hv);
                }
            }
        }
    }
}

// Phase B2: one workgroup per bucket. LDS per-node count -> LDS scan ->
// write off[] -> scatter to final CSR slots via LDS cursors.
__global__ __launch_bounds__(512) void k_partB2(
    int NB1, int NP, const int* __restrict__ bbase1, const uint2* __restrict__ stg1,
    unsigned* __restrict__ e1src, int* __restrict__ off1, int E1,
    int NC, const int* __restrict__ bbase2, const uint2* __restrict__ stg2,
    unsigned* __restrict__ epay, int* __restrict__ off2, int EPC) {
    __shared__ int cnt[512];
    __shared__ int cur[512];
    int b = blockIdx.x;
    int tid = threadIdx.x;
    if (b == 0 && tid < 32) {
        e1src[E1 + tid] = 0u;
        epay[EPC + tid] = 0u;
    }
    int n, n0, lo, hi;
    const uint2* stg; unsigned* dstp; int* off;
    if (b < NB1) {
        n = NP; n0 = b << 9; lo = bbase1[b]; hi = bbase1[b + 1];
        stg = stg1; dstp = e1src; off = off1;
    } else {
        int bb = b - NB1;
        n = NC; n0 = bb << 9; lo = bbase2[bb]; hi = bbase2[bb + 1];
        stg = stg2; dstp = epay; off = off2;
    }
    cnt[tid] = 0;
    __syncthreads();
    for (int i = lo + tid; i < hi; i += 512)
        atomicAdd(&cnt[stg[i].y & 511], 1);
    __syncthreads();
    int c0 = cnt[tid];
    for (int off_ = 1; off_ < 512; off_ <<= 1) {
        int t = (tid >= off_) ? cnt[tid - off_] : 0;
        __syncthreads();
        cnt[tid] += t;
        __syncthreads();
    }
    int pos0 = lo + cnt[tid] - c0;
    cur[tid] = pos0;
    int node = n0 + tid;
    if (node < n) off[node] = pos0;
    if (node == n - 1) off[n] = hi;
    __syncthreads();
    for (int i = lo + tid; i < hi; i += 512) {
        uint2 r = stg[i];
        int pos = atomicAdd(&cur[r.y & 511], 1);
        dstp[pos] = r.x;
    }
}

// ================= GATv2 building blocks =================

template <int CTRL>
__device__ __forceinline__ float dppadd_(float x) {
    int y = __builtin_amdgcn_update_dpp(0, __float_as_int(x), CTRL, 0xF, 0xF, true);
    return x + __int_as_float(y);
}

__device__ __forceinline__ float red16_(float c) {
    c = dppadd_<0xB1>(c);
    c = dppadd_<0x4E>(c);
    c = dppadd_<0x124>(c);
    c = dppadd_<0x128>(c);
    return c;
}

template <int HAS_EF>
__device__ __forceinline__ unsigned boff_(unsigned pr) {
    return HAS_EF ? ((pr & 0xFFFFu) << 7) : pr;
}

// Edge loop over fp16 rows; packed half2 math; no max-subtraction; DEPTH-4
// gather pipeline. Payload arrays zero-padded 32 entries.
template <int HAS_EF>
__device__ __forceinline__ void gat_pass(
    const void* __restrict__ hl, const unsigned* __restrict__ pay,
    int beg, int end, int slot, int g,
    f16x2 hr01, f16x2 hr23, f16x2 att01, f16x2 att23,
    f16x2 we01, f16x2 we23,
    float& s_run, float4& acc) {
    s_run = 0.f;
    acc = make_float4(0.f, 0.f, 0.f, 0.f);
    if (beg >= end) return;
    unsigned goff = (unsigned)g * 8u;
    int p = beg + slot;
    unsigned pr0 = pay[p], pr1 = pay[p + 4], pr2 = pay[p + 8],
             pr3 = pay[p + 12], pr4 = pay[p + 16];
    uint2 u0 = ld8_(hl, boff_<HAS_EF>(pr0) + goff);
    uint2 u1 = ld8_(hl, boff_<HAS_EF>(pr1) + goff);
    uint2 u2 = ld8_(hl, boff_<HAS_EF>(pr2) + goff);
    uint2 u3 = ld8_(hl, boff_<HAS_EF>(pr3) + goff);
    int pend = end + slot;
    for (; p < pend; p += 4) {
        unsigned prn = pay[p + 20];
        uint2 un = ld8_(hl, boff_<HAS_EF>(pr4) + goff);
        f16x2 m01 = *(f16x2*)&u0.x + hr01;
        f16x2 m23 = *(f16x2*)&u0.y + hr23;
        if (HAS_EF) {
            unsigned uh = pr0 & 0xFFFF0000u;
            unsigned lbu = uh | (uh >> 16);
            f16x2 lb2 = *(f16x2*)&lbu;
            m01 = lb2 * we01 + m01;
            m23 = lb2 * we23 + m23;
        }
        m01 = __builtin_elementwise_max(m01, m01 * (_Float16)0.2f);
        m23 = __builtin_elementwise_max(m23, m23 * (_Float16)0.2f);
        float c = fdot2_(m01, att01, 0.f);
        c = fdot2_(m23, att23, c);
        c = red16_(c);
        float w = (p < end) ? exp2f(c) : 0.f;
        s_run += w;
        float4 h = unpk_(u0);
        acc.x = fmaf(w, h.x, acc.x);
        acc.y = fmaf(w, h.y, acc.y);
        acc.z = fmaf(w, h.z, acc.z);
        acc.w = fmaf(w, h.w, acc.w);
        pr0 = pr1; pr1 = pr2; pr2 = pr3; pr3 = pr4; pr4 = prn;
        u0 = u1; u1 = u2; u2 = u3; u3 = un;
    }
}

__device__ __forceinline__ void slot_merge(float& s, float4& a) {
#pragma unroll
    for (int mask = 16; mask <= 32; mask <<= 1) {
        s += __shfl_xor(s, mask, 64);
        a.x += __shfl_xor(a.x, mask, 64);
        a.y += __shfl_xor(a.y, mask, 64);
        a.z += __shfl_xor(a.z, mask, 64);
        a.w += __shfl_xor(a.w, mask, 64);
    }
}

__device__ __forceinline__ void finish_row(float s_run, float4 a,
                                           const float* __restrict__ bias, int g,
                                           float o4[4]) {
    float inv = 1.f / (s_run + 1e-16f);
    float4 b4 = *(const float4*)(bias + g * 4);
    o4[0] = fmaxf(fmaf(a.x, inv, b4.x), 0.f);
    o4[1] = fmaxf(fmaf(a.y, inv, b4.y), 0.f);
    o4[2] = fmaxf(fmaf(a.z, inv, b4.z), 0.f);
    o4[3] = fmaxf(fmaf(a.w, inv, b4.w), 0.f);
}

// In-wave GEMV row@W via LDS row broadcast.
__device__ __forceinline__ float4 gemv64(const float o4[4], float* __restrict__ lds_row,
                                         int slot, int g, const float* __restrict__ W) {
    if (slot == 0) *(float4*)(lds_row + 4 * g) = make_float4(o4[0], o4[1], o4[2], o4[3]);
    __asm__ volatile("" ::: "memory");
    __builtin_amdgcn_wave_barrier();
    float4 r0 = *(const float4*)(lds_row + slot * 16 + 0);
    float4 r1 = *(const float4*)(lds_row + slot * 16 + 4);
    float4 r2 = *(const float4*)(lds_row + slot * 16 + 8);
    float4 r3 = *(const float4*)(lds_row + slot * 16 + 12);
    __asm__ volatile("" ::: "memory");
    __builtin_amdgcn_wave_barrier();
    float rv[16] = {r0.x, r0.y, r0.z, r0.w, r1.x, r1.y, r1.z, r1.w,
                    r2.x, r2.y, r2.z, r2.w, r3.x, r3.y, r3.z, r3.w};
    const float* Wp = W + slot * 16 * 64 + g * 4;
    float a0 = 0.f, a1 = 0.f, a2 = 0.f, a3 = 0.f;
#pragma unroll
    for (int t = 0; t < 16; ++t) {
        float4 w4 = *(const float4*)(Wp + t * 64);
        a0 = fmaf(rv[t], w4.x, a0); a1 = fmaf(rv[t], w4.y, a1);
        a2 = fmaf(rv[t], w4.z, a2); a3 = fmaf(rv[t], w4.w, a3);
    }
    a0 += __shfl_xor(a0, 16, 64); a0 += __shfl_xor(a0, 32, 64);
    a1 += __shfl_xor(a1, 16, 64); a1 += __shfl_xor(a1, 32, 64);
    a2 += __shfl_xor(a2, 16, 64); a2 += __shfl_xor(a2, 32, 64);
    a3 += __shfl_xor(a3, 16, 64); a3 += __shfl_xor(a3, 32, 64);
    return make_float4(a0, a1, a2, a3);
}

// conv1 (products): GAT + relu + @W3l + b3l -> hl3 (fp16). hr1 is fp16 rows.
__global__ __launch_bounds__(256) void k_gat1(
    const void* __restrict__ hl, const void* __restrict__ hr,
    const int* __restrict__ offs, const unsigned* __restrict__ esrc,
    const float* __restrict__ att, const float* __restrict__ bias,
    const float* __restrict__ W2, const float* __restrict__ b2,
    void* __restrict__ out2, int ndst) {
    __shared__ float rowbuf[4][64];
    int wid = (blockIdx.x * blockDim.x + threadIdx.x) >> 6;
    if (wid >= ndst) return;
    int lane = threadIdx.x & 63, slot = lane >> 4, g = lane & 15;
    float* lrow = rowbuf[threadIdx.x >> 6];
    const float L2E = 1.44269504f;
    uint2 hu = *(const uint2*)((const char*)hr + (size_t)wid * 128 + g * 8);
    f16x2 hr01 = *(f16x2*)&hu.x, hr23 = *(f16x2*)&hu.y;
    float4 at = *(const float4*)(att + g * 4);
    f16x2 att01 = pkc_(at.x * L2E, at.y * L2E), att23 = pkc_(at.z * L2E, at.w * L2E);
    int beg = offs[wid], end = offs[wid + 1];
    float s; float4 a;
    gat_pass<0>(hl, esrc, beg, end, slot, g, hr01, hr23, att01, att23, att01, att23, s, a);
    slot_merge(s, a);
    float o4[4];
    finish_row(s, a, bias, g, o4);
    float4 o = gemv64(o4, lrow, slot, g, W2);
    float4 bb = *(const float4*)(b2 + g * 4);
    o.x += bb.x; o.y += bb.y; o.z += bb.z; o.w += bb.w;
    if (slot == 0)
        *(uint2*)((char*)out2 + (size_t)wid * 128 + g * 8) =
            make_uint2(pkh_(o.x, o.y), pkh_(o.z, o.w));
}

// conv2 + conv3 fused per customer node: conv3's hr (h3) stays in registers.
__global__ __launch_bounds__(256) void k_gat23(
    const void* __restrict__ hl2, const void* __restrict__ hr2,
    const void* __restrict__ hl3,
    const int* __restrict__ off2, const unsigned* __restrict__ epay,
    const float* __restrict__ We2, const float* __restrict__ att2, const float* __restrict__ bias2,
    const float* __restrict__ W3r, const float* __restrict__ b3r,
    const float* __restrict__ We3, const float* __restrict__ att3, const float* __restrict__ bias3,
    const float* __restrict__ Wlin, const float* __restrict__ blin,
    float* __restrict__ outp, int ndst) {
    __shared__ float rowbuf[4][64];
    int wid = (blockIdx.x * blockDim.x + threadIdx.x) >> 6;
    if (wid >= ndst) return;
    int lane = threadIdx.x & 63, slot = lane >> 4, g = lane & 15;
    float* lrow = rowbuf[threadIdx.x >> 6];
    int beg = off2[wid], end = off2[wid + 1];
    const float L2E = 1.44269504f;
    // ---- conv2 ----
    uint2 hu = *(const uint2*)((const char*)hr2 + (size_t)wid * 128 + g * 8);
    f16x2 hr01 = *(f16x2*)&hu.x, hr23 = *(f16x2*)&hu.y;
    float4 at = *(const float4*)(att2 + g * 4);
    f16x2 att01 = pkc_(at.x * L2E, at.y * L2E), att23 = pkc_(at.z * L2E, at.w * L2E);
    float4 wef = *(const float4*)(We2 + g * 4);
    f16x2 we01 = pkc_(wef.x, wef.y), we23 = pkc_(wef.z, wef.w);
    float s; float4 a;
    gat_pass<1>(hl2, epay, beg, end, slot, g, hr01, hr23, att01, att23, we01, we23, s, a);
    slot_merge(s, a);
    float o4[4];
    finish_row(s, a, bias2, g, o4);
    float4 h3 = gemv64(o4, lrow, slot, g, W3r);
    float4 bb = *(const float4*)(b3r + g * 4);
    h3.x += bb.x; h3.y += bb.y; h3.z += bb.z; h3.w += bb.w;
    // ---- conv3 (h3 in registers) ----
    hr01 = pkc_(h3.x, h3.y); hr23 = pkc_(h3.z, h3.w);
    at = *(const float4*)(att3 + g * 4);
    att01 = pkc_(at.x * L2E, at.y * L2E); att23 = pkc_(at.z * L2E, at.w * L2E);
    wef = *(const float4*)(We3 + g * 4);
    we01 = pkc_(wef.x, wef.y); we23 = pkc_(wef.z, wef.w);
    gat_pass<1>(hl3, epay, beg, end, slot, g, hr01, hr23, att01, att23, we01, we23, s, a);
    slot_merge(s, a);
    finish_row(s, a, bias3, g, o4);
    float4 o = gemv64(o4, lrow, slot, g, Wlin);
    float4 bl = *(const float4*)(blin + g * 4);
    o.x += bl.x; o.y += bl.y; o.z += bl.z; o.w += bl.w;
    if (slot == 0) *(float4*)(outp + (size_t)wid * 64 + g * 4) = o;
}

// ================= launch =================

extern "C" void kernel_launch(void* const* d_in, const int* in_sizes, int n_in,
                              void* d_out, int out_size, void* d_ws, size_t ws_size,
                              hipStream_t stream) {
    const float* x_p = (const float*)d_in[0];
    const float* x_c = (const float*)d_in[1];
    const float* elab_in = (const float*)d_in[2];
    const int* src_pp = (const int*)d_in[3];
    const int* dst_pp = (const int*)d_in[4];
    const int* src_pc = (const int*)d_in[5];
    const int* dst_pc = (const int*)d_in[6];
    const float* W1l = (const float*)d_in[7];
    const float* b1l = (const float*)d_in[8];
    const float* W1r = (const float*)d_in[9];
    const float* b1r = (const float*)d_in[10];
    const float* att1 = (const float*)d_in[11];
    const float* bias1 = (const float*)d_in[12];
    const float* W2l = (const float*)d_in[13];
    const float* b2l = (const float*)d_in[14];
    const float* W2r = (const float*)d_in[15];
    const float* b2r = (const float*)d_in[16];
    const float* We2 = (const float*)d_in[17];
    const float* att2 = (const float*)d_in[18];
    const float* bias2 = (const float*)d_in[19];
    const float* W3l = (const float*)d_in[20];
    const float* b3l = (const float*)d_in[21];
    const float* W3r = (const float*)d_in[22];
    const float* b3r = (const float*)d_in[23];
    const float* We3 = (const float*)d_in[24];
    const float* att3 = (const float*)d_in[25];
    const float* bias3 = (const float*)d_in[26];
    const float* Wlin = (const float*)d_in[27];
    const float* blin = (const float*)d_in[28];
    float* out = (float*)d_out;

    const int NP = in_sizes[0] / 64;
    const int NC = in_sizes[1] / 64;
    const int EPP = in_sizes[3];
    const int EPC = in_sizes[5];
    const int E1 = EPP + NP;
    const int NB1 = ceil_div(NP, 512), NB2 = ceil_div(NC, 512);

    // workspace layout (256B-aligned chunks) — all feature arrays fp16
    char* w = (char*)d_ws;
    auto alloc = [&](size_t bytes) { char* r = w; w += (bytes + 255) & ~(size_t)255; return r; };
    void* hl1 = alloc((size_t)NP * 128);
    void* hl2 = alloc((size_t)NP * 128);
    void* hl3 = alloc((size_t)NP * 128);
    void* hr1 = alloc((size_t)NP * 128);
    void* hr2 = alloc((size_t)NC * 128);
    unsigned* epay = (unsigned*)alloc((size_t)(EPC + 32) * 4);
    unsigned* e1src = (unsigned*)alloc((size_t)(E1 + 32) * 4);
    uint2* stg1 = (uint2*)alloc((size_t)E1 * 8);
    uint2* stg2 = (uint2*)alloc((size_t)EPC * 8);
    int* off1 = (int*)alloc((size_t)(NP + 1) * 4);
    int* off2 = (int*)alloc((size_t)(NC + 1) * 4);
    int* btot1 = (int*)alloc(256 * 4);
    int* btot2 = (int*)alloc(256 * 4);
    int* bbase1 = (int*)alloc(260 * 4);
    int* bbase2 = (int*)alloc(260 * 4);
    int* bcur1 = (int*)alloc(256 * 4);
    int* bcur2 = (int*)alloc(256 * 4);

    int NH1 = ceil_div(EPP, PART_CHUNK), NH2 = ceil_div(EPC, PART_CHUNK);
    int NA1 = ceil_div(E1, PART_CHUNK), NA2 = ceil_div(EPC, PART_CHUNK);

    (void)hipMemsetAsync(btot1, 0, 256 * 4, stream);
    (void)hipMemsetAsync(btot2, 0, 256 * 4, stream);

    // setup: bucket histograms
    k_pre<<<NH1 + NH2, 256, 0, stream>>>(dst_pp, EPP, NH1, dst_pc, EPC, btot1, btot2);
    k_bscan<<<dim3(1, 2), 256, 0, stream>>>(NP, NB1, btot1, bbase1, bcur1,
                                            NC, NB2, btot2, bbase2, bcur2);

    // fused: edge partition + input GEMMs (both low-VGPR now)
    int TP = ceil_div(NP, 32), TC = ceil_div(NC, 32);
    k_AG<<<NA1 + NA2 + 3 * TP + TC, 256, 0, stream>>>(
        NP, src_pp, dst_pp, E1, src_pc, dst_pc, elab_in, EPC, NA1, NA2,
        bcur1, bcur2, stg1, stg2,
        TP, x_p, x_c, NC,
        W1l, b1l, hl1, W1r, b1r, hr1, W2l, b2l, hl2, W2r, b2r, hr2);

    // bucket-local CSR finalize
    k_partB2<<<NB1 + NB2, 512, 0, stream>>>(
        NB1, NP, bbase1, stg1, e1src, off1, E1,
        NC, bbase2, stg2, epay, off2, EPC);

    // conv1 -> hl3 (fp16)
    k_gat1<<<ceil_div(NP * 64, 256), 256, 0, stream>>>(
        hl1, hr1, off1, e1src, att1, bias1, W3l, b3l, hl3, NP);

    // conv2+conv3 fused -> d_out (h3 stays in registers)
    k_gat23<<<ceil_div(NC * 64, 256), 256, 0, stream>>>(
        hl2, hr2, hl3, off2, epay, We2, att2, bias2, W3r, b3r,
        We3, att3, bias3, Wlin, blin, out, NC);
}